// Round 2
// baseline (1125.835 us; speedup 1.0000x reference)
//
#include <hip/hip_runtime.h>
#include <hip/hip_bf16.h>

// GATv2 3-layer, N=80000 E=1280000 FIN=128 H=64 OUT=10. fp32 compute.
// Input/output storage dtype (bf16 vs fp32) detected at runtime on-device
// (flag in ws, recomputed every call -> graph-safe).
//  - per-call preprocess: CSR by dst (hist + scan + scatter), weights -> fp32 transposed
//  - lin: per-wave 64-node tile, x staged in LDS (padded), W via wave-uniform streams
//  - agg: one wave per dst node, online softmax over in-edges + self-loop
//  - readout: wave per node, 10 butterfly reductions

#define NN 80000
#define EE 1280000
#define FIN 128
#define HH 64
#define OUTD 10

typedef __hip_bfloat16 bf16;

__device__ __forceinline__ float b2f(bf16 v) { return __bfloat162float(v); }

// load element i of a tensor whose storage dtype is flag ? bf16 : float32
__device__ __forceinline__ float ldw(const void* p, int i, int f) {
    return f ? __bfloat162float(((const bf16*)p)[i]) : ((const float*)p)[i];
}

// ---------------- dtype detect ----------------
// Decode first 2048 u32 of Wl0 as bf16 pairs. Genuine bf16 weights: |v| <= ~1.
// float32 storage: low-16 halves decode to huge/NaN bf16 with ~46% prob each.
__global__ void detect_kernel(const unsigned* __restrict__ w, int* __restrict__ flag) {
    int lane = threadIdx.x;
    int big = 0;
    for (int i = lane; i < 2048; i += 64) {
        unsigned u = w[i];
        float a = __uint_as_float(u << 16);
        float b = __uint_as_float(u & 0xffff0000u);
        if (!(fabsf(a) <= 1024.f)) big = 1;   // NaN also trips (comparison false)
        if (!(fabsf(b) <= 1024.f)) big = 1;
    }
    big = (__ballot(big) != 0ull) ? 1 : 0;
    if (lane == 0) flag[0] = big ? 0 : 1;     // 1 = bf16 storage, 0 = fp32 storage
}

// ---------------- preconvert weights ----------------
__global__ void preconvert(
    const void* Wl0, const void* Wr0, const void* Wl1, const void* Wr1,
    const void* Wl2, const void* Wr2,
    const void* bl0, const void* br0, const void* bl1, const void* br1,
    const void* bl2, const void* br2,
    const void* att0, const void* att1, const void* att2,
    const void* b0, const void* b1, const void* b2,
    const void* Wro, const void* bro,
    float* WT0, float* WT1, float* WT2, float* small,
    const int* __restrict__ flagp)
{
    const int f = flagp[0];
    int t = blockIdx.x * 256 + threadIdx.x;
    if (t < 16384) {                       // WT0: F=128, 128 outputs
        int j = t & 127, k = t >> 7;       // k<128
        float v = (j < 64) ? ldw(Wl0, j * 128 + k, f) : ldw(Wr0, (j - 64) * 128 + k, f);
        WT0[(j >> 3) * (128 * 8) + k * 8 + (j & 7)] = v;
    } else if (t < 24576) {                // WT1: F=64
        int u = t - 16384; int j = u & 127, k = u >> 7; // k<64
        float v = (j < 64) ? ldw(Wl1, j * 64 + k, f) : ldw(Wr1, (j - 64) * 64 + k, f);
        WT1[(j >> 3) * (64 * 8) + k * 8 + (j & 7)] = v;
    } else if (t < 32768) {                // WT2: F=64
        int u = t - 24576; int j = u & 127, k = u >> 7;
        float v = (j < 64) ? ldw(Wl2, j * 64 + k, f) : ldw(Wr2, (j - 64) * 64 + k, f);
        WT2[(j >> 3) * (64 * 8) + k * 8 + (j & 7)] = v;
    } else if (t < 34304) {
        int s = t - 32768;
        const void* BL[3] = { bl0, bl1, bl2 };
        const void* BR[3] = { br0, br1, br2 };
        const void* AT[3] = { att0, att1, att2 };
        const void* BB[3] = { b0, b1, b2 };
        float v = 0.f;
        if (s < 384) {                     // biasLR: 3 layers x 128 (bl|br)
            int l = s / 128, r = s % 128;
            v = (r < 64) ? ldw(BL[l], r, f) : ldw(BR[l], r - 64, f);
        } else if (s < 576) {              // att: 3 x 64
            int q = s - 384; v = ldw(AT[q / 64], q % 64, f);
        } else if (s < 768) {              // b (post-agg bias): 3 x 64
            int q = s - 576; v = ldw(BB[q / 64], q % 64, f);
        } else if (s < 1408) {             // Wro 10x64
            v = ldw(Wro, s - 768, f);
        } else if (s < 1418) {             // bro
            v = ldw(bro, s - 1408, f);
        } else return;
        small[s] = v;
    }
}

// ---------------- CSR build ----------------
__global__ void hist_kernel(const int* __restrict__ dst, int* __restrict__ cnt) {
    int k = blockIdx.x * 256 + threadIdx.x;
    if (k < EE) atomicAdd(&cnt[dst[k]], 1);
}

__global__ void scan1(const int* __restrict__ cnt, int* __restrict__ rowptr,
                      int* __restrict__ bsums) {
    __shared__ int sh[256];
    int i = blockIdx.x * 256 + threadIdx.x;
    int tid = threadIdx.x;
    sh[tid] = (i < NN) ? cnt[i] : 0;
    __syncthreads();
    #pragma unroll
    for (int off = 1; off < 256; off <<= 1) {
        int t = (tid >= off) ? sh[tid - off] : 0;
        __syncthreads();
        sh[tid] += t;
        __syncthreads();
    }
    if (i < NN) rowptr[i + 1] = sh[tid];
    if (tid == 255) bsums[blockIdx.x] = sh[255];
}

__global__ void scan2(int* __restrict__ bsums, int nb) {
    __shared__ int sh[512];
    int t = threadIdx.x;
    sh[t] = (t < nb) ? bsums[t] : 0;
    __syncthreads();
    #pragma unroll
    for (int off = 1; off < 512; off <<= 1) {
        int v = (t >= off) ? sh[t - off] : 0;
        __syncthreads();
        sh[t] += v;
        __syncthreads();
    }
    if (t < nb) bsums[t] = sh[t];
}

__global__ void scan3(int* __restrict__ rowptr, const int* __restrict__ bsums) {
    int i = blockIdx.x * 256 + threadIdx.x;
    if (i == 0) rowptr[0] = 0;
    int add = (blockIdx.x == 0) ? 0 : bsums[blockIdx.x - 1];
    if (i < NN) rowptr[i + 1] += add;
}

__global__ void scatter_kernel(const int* __restrict__ src, const int* __restrict__ dst,
                               int* __restrict__ fill, int* __restrict__ col) {
    int k = blockIdx.x * 256 + threadIdx.x;
    if (k < EE) {
        int d = dst[k];
        int pos = atomicAdd(&fill[d], 1);
        col[pos] = src[k];
    }
}

// ---------------- layer-0 linear: F=128, x storage dtype via flag ----------------
__global__ __launch_bounds__(64) void lin0_kernel(const void* __restrict__ hin_,
                                                  const float* __restrict__ WT,
                                                  const float* __restrict__ biasLR,
                                                  float* __restrict__ xl,
                                                  float* __restrict__ xr,
                                                  const int* __restrict__ flagp)
{
    constexpr int F = 128, LDF = F + 1;
    __shared__ float xs[64 * LDF];
    const int lane = threadIdx.x;
    const int nb = blockIdx.x * 64;
    const int f = flagp[0];

    if (f) {
        const unsigned* hp = (const unsigned*)hin_;
        for (int r = 0; r < 64; r++) {
            unsigned u = hp[(size_t)(nb + r) * (F / 2) + lane];
            xs[r * LDF + 2 * lane]     = __uint_as_float(u << 16);
            xs[r * LDF + 2 * lane + 1] = __uint_as_float(u & 0xffff0000u);
        }
    } else {
        const float* hp = (const float*)hin_;
        for (int r = 0; r < 64; r++) {
            xs[r * LDF + lane]      = hp[(size_t)(nb + r) * F + lane];
            xs[r * LDF + 64 + lane] = hp[(size_t)(nb + r) * F + 64 + lane];
        }
    }
    __syncthreads();

    const size_t node = nb + lane;
    #pragma unroll 1
    for (int jt = 0; jt < 16; jt++) {
        float acc[8];
        #pragma unroll
        for (int u = 0; u < 8; u++) acc[u] = biasLR[jt * 8 + u];
        const float* wp = WT + (size_t)jt * F * 8;
        #pragma unroll 4
        for (int k = 0; k < F; k++) {
            float xv = xs[lane * LDF + k];
            #pragma unroll
            for (int u = 0; u < 8; u++) acc[u] = fmaf(xv, wp[k * 8 + u], acc[u]);
        }
        int j0 = jt * 8;
        float* dptr = (j0 < 64) ? (xl + node * 64 + j0) : (xr + node * 64 + (j0 - 64));
        *(float4*)dptr = make_float4(acc[0], acc[1], acc[2], acc[3]);
        *(float4*)(dptr + 4) = make_float4(acc[4], acc[5], acc[6], acc[7]);
    }
}

// ---------------- layers 1/2 linear: F=64, fp32 ws input ----------------
__global__ __launch_bounds__(64) void lin64_kernel(const float* __restrict__ hin,
                                                   const float* __restrict__ WT,
                                                   const float* __restrict__ biasLR,
                                                   float* __restrict__ xl,
                                                   float* __restrict__ xr)
{
    constexpr int F = 64, LDF = F + 1;
    __shared__ float xs[64 * LDF];
    const int lane = threadIdx.x;
    const int nb = blockIdx.x * 64;

    for (int r = 0; r < 64; r++)
        xs[r * LDF + lane] = hin[(size_t)(nb + r) * F + lane];
    __syncthreads();

    const size_t node = nb + lane;
    #pragma unroll 1
    for (int jt = 0; jt < 16; jt++) {
        float acc[8];
        #pragma unroll
        for (int u = 0; u < 8; u++) acc[u] = biasLR[jt * 8 + u];
        const float* wp = WT + (size_t)jt * F * 8;
        #pragma unroll 4
        for (int k = 0; k < F; k++) {
            float xv = xs[lane * LDF + k];
            #pragma unroll
            for (int u = 0; u < 8; u++) acc[u] = fmaf(xv, wp[k * 8 + u], acc[u]);
        }
        int j0 = jt * 8;
        float* dptr = (j0 < 64) ? (xl + node * 64 + j0) : (xr + node * 64 + (j0 - 64));
        *(float4*)dptr = make_float4(acc[0], acc[1], acc[2], acc[3]);
        *(float4*)(dptr + 4) = make_float4(acc[4], acc[5], acc[6], acc[7]);
    }
}

// ---------------- aggregation: online softmax over in-edges + self loop ----------------
__global__ __launch_bounds__(256) void agg_kernel(const float* __restrict__ xl,
                                                  const float* __restrict__ xr,
                                                  const float* __restrict__ attf,
                                                  const float* __restrict__ bf,
                                                  const int* __restrict__ rowptr,
                                                  const int* __restrict__ col,
                                                  float* __restrict__ hout)
{
    const int lane = threadIdx.x & 63;
    const int i = blockIdx.x * 4 + (threadIdx.x >> 6);
    if (i >= NN) return;

    const float a = attf[lane];
    const float r = xr[(size_t)i * 64 + lane];
    const float xli = xl[(size_t)i * 64 + lane];

    // self loop first (every node has exactly one appended)
    float t = xli + r;
    float p = (t > 0.f ? t : 0.2f * t) * a;
    #pragma unroll
    for (int off = 1; off < 64; off <<= 1) p += __shfl_xor(p, off, 64);
    float m = p;
    float denom = 1.f;
    float acc = xli;

    int e0 = rowptr[i], e1 = rowptr[i + 1];
    float xN = 0.f;
    if (e0 < e1) { int s0 = col[e0]; xN = xl[(size_t)s0 * 64 + lane]; }
    for (int e = e0; e < e1; e++) {
        float xsv = xN;
        if (e + 1 < e1) { int s2 = col[e + 1]; xN = xl[(size_t)s2 * 64 + lane]; }
        float tt = xsv + r;
        float pp = (tt > 0.f ? tt : 0.2f * tt) * a;
        #pragma unroll
        for (int off = 1; off < 64; off <<= 1) pp += __shfl_xor(pp, off, 64);
        if (pp > m) {
            float sc = __expf(m - pp);
            denom = denom * sc + 1.f;
            acc = acc * sc + xsv;
            m = pp;
        } else {
            float w = __expf(pp - m);
            denom += w;
            acc += w * xsv;
        }
    }
    float o = acc / denom + bf[lane];
    hout[(size_t)i * 64 + lane] = fmaxf(o, 0.f);
}

// ---------------- readout: out = h @ Wro^T + bro, output dtype via flag ----------------
__global__ __launch_bounds__(256) void readout_kernel(const float* __restrict__ h,
                                                      const float* __restrict__ WROf,
                                                      const float* __restrict__ brof,
                                                      void* __restrict__ out,
                                                      const int* __restrict__ flagp)
{
    const int lane = threadIdx.x & 63;
    const int i = blockIdx.x * 4 + (threadIdx.x >> 6);
    if (i >= NN) return;
    const int f = flagp[0];
    float hv = h[(size_t)i * 64 + lane];
    float res = 0.f;
    #pragma unroll
    for (int o = 0; o < OUTD; o++) {
        float p = hv * WROf[o * 64 + lane];
        #pragma unroll
        for (int off = 1; off < 64; off <<= 1) p += __shfl_xor(p, off, 64);
        if (lane == o) res = p + brof[o];
    }
    if (lane < OUTD) {
        if (f) ((bf16*)out)[(size_t)i * OUTD + lane] = __float2bfloat16(res);
        else   ((float*)out)[(size_t)i * OUTD + lane] = res;
    }
}

extern "C" void kernel_launch(void* const* d_in, const int* in_sizes, int n_in,
                              void* d_out, int out_size, void* d_ws, size_t ws_size,
                              hipStream_t stream) {
    const void* x   = d_in[0];
    const int* ei   = (const int*)d_in[1];
    // d_in[2] = batch (unused)
    const void* Wl0 = d_in[3];  const void* bl0 = d_in[4];
    const void* Wr0 = d_in[5];  const void* br0 = d_in[6];
    const void* at0 = d_in[7];  const void* b0  = d_in[8];
    const void* Wl1 = d_in[9];  const void* bl1 = d_in[10];
    const void* Wr1 = d_in[11]; const void* br1 = d_in[12];
    const void* at1 = d_in[13]; const void* b1  = d_in[14];
    const void* Wl2 = d_in[15]; const void* bl2 = d_in[16];
    const void* Wr2 = d_in[17]; const void* br2 = d_in[18];
    const void* at2 = d_in[19]; const void* b2  = d_in[20];
    const void* Wro = d_in[21]; const void* bro = d_in[22];

    const int* srcArr = ei;
    const int* dstArr = ei + EE;

    // workspace layout (float-indexed)
    float* wf = (float*)d_ws;
    float* WT0   = wf;                       // 16384
    float* WT1   = wf + 16384;               // 8192
    float* WT2   = wf + 24576;               // 8192
    float* small = wf + 32768;               // 1536
    int*   flag  = (int*)(wf + 34304);       // 1 (pad 64)
    int*   rowptr = (int*)(wf + 34368);      // 80001 (pad to 80128)
    int*   bsums  = (int*)(wf + 34368 + 80128);        // 512
    int*   fill   = (int*)(wf + 34368 + 80128 + 512);  // 80000
    int*   col    = (int*)(wf + 34368 + 80128 + 512 + 80000); // 1280000
    float* xl = wf + 1475008;                // 5120000 each
    float* xr = xl + (size_t)NN * 64;
    float* hA = xr + (size_t)NN * 64;
    float* hB = hA + (size_t)NN * 64;

    float* biasLR0 = small;        float* biasLR1 = small + 128; float* biasLR2 = small + 256;
    float* attf0 = small + 384;    float* attf1 = small + 448;   float* attf2 = small + 512;
    float* bf0   = small + 576;    float* bf1   = small + 640;   float* bf2   = small + 704;
    float* WROf  = small + 768;    float* brof  = small + 1408;

    // 0) detect storage dtype from Wl0
    detect_kernel<<<dim3(1), dim3(64), 0, stream>>>((const unsigned*)Wl0, flag);

    // 1) convert weights
    preconvert<<<dim3(134), dim3(256), 0, stream>>>(
        Wl0, Wr0, Wl1, Wr1, Wl2, Wr2, bl0, br0, bl1, br1, bl2, br2,
        at0, at1, at2, b0, b1, b2, Wro, bro, WT0, WT1, WT2, small, flag);

    // 2) CSR build (by dst); self-loops handled analytically in agg
    hipMemsetAsync(fill, 0, (size_t)NN * 4, stream);
    hist_kernel<<<dim3(EE / 256), dim3(256), 0, stream>>>(dstArr, fill);
    scan1<<<dim3(313), dim3(256), 0, stream>>>(fill, rowptr, bsums);
    scan2<<<dim3(1), dim3(512), 0, stream>>>(bsums, 313);
    scan3<<<dim3(313), dim3(256), 0, stream>>>(rowptr, bsums);
    hipMemcpyAsync(fill, rowptr, (size_t)NN * 4, hipMemcpyDeviceToDevice, stream);
    scatter_kernel<<<dim3(EE / 256), dim3(256), 0, stream>>>(srcArr, dstArr, fill, col);

    // 3) layers
    lin0_kernel<<<dim3(NN / 64), dim3(64), 0, stream>>>(x, WT0, biasLR0, xl, xr, flag);
    agg_kernel<<<dim3(NN / 4), dim3(256), 0, stream>>>(xl, xr, attf0, bf0, rowptr, col, hA);

    lin64_kernel<<<dim3(NN / 64), dim3(64), 0, stream>>>(hA, WT1, biasLR1, xl, xr);
    agg_kernel<<<dim3(NN / 4), dim3(256), 0, stream>>>(xl, xr, attf1, bf1, rowptr, col, hB);

    lin64_kernel<<<dim3(NN / 64), dim3(64), 0, stream>>>(hB, WT2, biasLR2, xl, xr);
    agg_kernel<<<dim3(NN / 4), dim3(256), 0, stream>>>(xl, xr, attf2, bf2, rowptr, col, hA);

    // 4) readout
    readout_kernel<<<dim3(NN / 4), dim3(256), 0, stream>>>(hA, WROf, brof, d_out, flag);
}

// Round 3
// 824.118 us; speedup vs baseline: 1.3661x; 1.3661x over previous
//
#include <hip/hip_runtime.h>
#include <hip/hip_bf16.h>

// GATv2 3-layer, N=80000 E=1280000 FIN=128 H=64 OUT=10. fp32 compute.
// Round 3: lin kernels restructured for occupancy (250us -> ~25us predicted):
//   block=256, 64-node tile, 8x4 register tile/thread, x staged transposed in
//   LDS (ds_read_b128), W in [k][j] layout (coalesced float4 streams).
// CSR build + online-softmax agg + wave-per-node readout unchanged.

#define NN 80000
#define EE 1280000
#define FIN 128
#define HH 64
#define OUTD 10

typedef __hip_bfloat16 bf16;

__device__ __forceinline__ float ldw(const void* p, int i, int f) {
    return f ? __bfloat162float(((const bf16*)p)[i]) : ((const float*)p)[i];
}

// ---------------- dtype detect ----------------
__global__ void detect_kernel(const unsigned* __restrict__ w, int* __restrict__ flag) {
    int lane = threadIdx.x;
    int big = 0;
    for (int i = lane; i < 2048; i += 64) {
        unsigned u = w[i];
        float a = __uint_as_float(u << 16);
        float b = __uint_as_float(u & 0xffff0000u);
        if (!(fabsf(a) <= 1024.f)) big = 1;
        if (!(fabsf(b) <= 1024.f)) big = 1;
    }
    big = (__ballot(big) != 0ull) ? 1 : 0;
    if (lane == 0) flag[0] = big ? 0 : 1;     // 1 = bf16 storage, 0 = fp32
}

// ---------------- preconvert weights ----------------
// WT layout now [k][j]: WT[k*128 + j] = (j<64 ? Wl[j][k] : Wr[j-64][k])
__global__ void preconvert(
    const void* Wl0, const void* Wr0, const void* Wl1, const void* Wr1,
    const void* Wl2, const void* Wr2,
    const void* bl0, const void* br0, const void* bl1, const void* br1,
    const void* bl2, const void* br2,
    const void* att0, const void* att1, const void* att2,
    const void* b0, const void* b1, const void* b2,
    const void* Wro, const void* bro,
    float* WT0, float* WT1, float* WT2, float* small,
    const int* __restrict__ flagp)
{
    const int f = flagp[0];
    int t = blockIdx.x * 256 + threadIdx.x;
    if (t < 16384) {                       // WT0: k<128
        int j = t & 127, k = t >> 7;
        float v = (j < 64) ? ldw(Wl0, j * 128 + k, f) : ldw(Wr0, (j - 64) * 128 + k, f);
        WT0[k * 128 + j] = v;
    } else if (t < 24576) {                // WT1: k<64
        int u = t - 16384; int j = u & 127, k = u >> 7;
        float v = (j < 64) ? ldw(Wl1, j * 64 + k, f) : ldw(Wr1, (j - 64) * 64 + k, f);
        WT1[k * 128 + j] = v;
    } else if (t < 32768) {                // WT2: k<64
        int u = t - 24576; int j = u & 127, k = u >> 7;
        float v = (j < 64) ? ldw(Wl2, j * 64 + k, f) : ldw(Wr2, (j - 64) * 64 + k, f);
        WT2[k * 128 + j] = v;
    } else if (t < 34304) {
        int s = t - 32768;
        const void* BL[3] = { bl0, bl1, bl2 };
        const void* BR[3] = { br0, br1, br2 };
        const void* AT[3] = { att0, att1, att2 };
        const void* BB[3] = { b0, b1, b2 };
        float v = 0.f;
        if (s < 384) {
            int l = s / 128, r = s % 128;
            v = (r < 64) ? ldw(BL[l], r, f) : ldw(BR[l], r - 64, f);
        } else if (s < 576) {
            int q = s - 384; v = ldw(AT[q / 64], q % 64, f);
        } else if (s < 768) {
            int q = s - 576; v = ldw(BB[q / 64], q % 64, f);
        } else if (s < 1408) {
            v = ldw(Wro, s - 768, f);
        } else if (s < 1418) {
            v = ldw(bro, s - 1408, f);
        } else return;
        small[s] = v;
    }
}

// ---------------- CSR build ----------------
__global__ void hist_kernel(const int* __restrict__ dst, int* __restrict__ cnt) {
    int k = blockIdx.x * 256 + threadIdx.x;
    if (k < EE) atomicAdd(&cnt[dst[k]], 1);
}

__global__ void scan1(const int* __restrict__ cnt, int* __restrict__ rowptr,
                      int* __restrict__ bsums) {
    __shared__ int sh[256];
    int i = blockIdx.x * 256 + threadIdx.x;
    int tid = threadIdx.x;
    sh[tid] = (i < NN) ? cnt[i] : 0;
    __syncthreads();
    #pragma unroll
    for (int off = 1; off < 256; off <<= 1) {
        int t = (tid >= off) ? sh[tid - off] : 0;
        __syncthreads();
        sh[tid] += t;
        __syncthreads();
    }
    if (i < NN) rowptr[i + 1] = sh[tid];
    if (tid == 255) bsums[blockIdx.x] = sh[255];
}

__global__ void scan2(int* __restrict__ bsums, int nb) {
    __shared__ int sh[512];
    int t = threadIdx.x;
    sh[t] = (t < nb) ? bsums[t] : 0;
    __syncthreads();
    #pragma unroll
    for (int off = 1; off < 512; off <<= 1) {
        int v = (t >= off) ? sh[t - off] : 0;
        __syncthreads();
        sh[t] += v;
        __syncthreads();
    }
    if (t < nb) bsums[t] = sh[t];
}

__global__ void scan3(int* __restrict__ rowptr, const int* __restrict__ bsums) {
    int i = blockIdx.x * 256 + threadIdx.x;
    if (i == 0) rowptr[0] = 0;
    int add = (blockIdx.x == 0) ? 0 : bsums[blockIdx.x - 1];
    if (i < NN) rowptr[i + 1] += add;
}

__global__ void scatter_kernel(const int* __restrict__ src, const int* __restrict__ dst,
                               int* __restrict__ fill, int* __restrict__ col) {
    int k = blockIdx.x * 256 + threadIdx.x;
    if (k < EE) {
        int d = dst[k];
        int pos = atomicAdd(&fill[d], 1);
        col[pos] = src[k];
    }
}

// ---------------- linear (high-occupancy): xl|xr = h @ [Wl|Wr]^T + [bl|br] ----
// block=256, tile = 64 nodes x 128 cols; thread (c=t&31, g=t>>5): 8 rows x 4 cols.
// xs transposed: xs[k*72 + row]  (72 = 64 + 8 pad, keeps b128 alignment).
template<int F, bool L0>
__global__ __launch_bounds__(256) void lin_fast(const void* __restrict__ hin_,
                                                const float* __restrict__ WT,
                                                const float* __restrict__ biasLR,
                                                float* __restrict__ xl,
                                                float* __restrict__ xr,
                                                const int* __restrict__ flagp)
{
    constexpr int LDR = 72;
    __shared__ __align__(16) float xs[F * LDR];
    const int t = threadIdx.x;
    const int nb = blockIdx.x * 64;

    if (L0 && flagp[0]) {
        const unsigned* hp = (const unsigned*)hin_;
        for (int idx = t; idx < 64 * (F / 2); idx += 256) {
            int r = idx / (F / 2), c = idx % (F / 2);
            unsigned u = hp[(size_t)(nb + r) * (F / 2) + c];
            xs[(2 * c) * LDR + r]     = __uint_as_float(u << 16);
            xs[(2 * c + 1) * LDR + r] = __uint_as_float(u & 0xffff0000u);
        }
    } else {
        const float* hp = (const float*)hin_;
        for (int idx = t; idx < 64 * F; idx += 256) {
            int r = idx / F, c = idx % F;
            xs[c * LDR + r] = hp[(size_t)(nb + r) * F + c];
        }
    }
    __syncthreads();

    const int c = t & 31;          // col group: j0 = 4c
    const int g = t >> 5;          // row group: rows g*8 .. g*8+7
    const float4* W4 = (const float4*)WT;
    const float4 bias = ((const float4*)biasLR)[c];
    float4 acc[8];
    #pragma unroll
    for (int u = 0; u < 8; u++) acc[u] = bias;

    #pragma unroll 2
    for (int k = 0; k < F; k++) {
        float4 w  = W4[k * 32 + c];
        float4 xa = *(const float4*)&xs[k * LDR + g * 8];
        float4 xb = *(const float4*)&xs[k * LDR + g * 8 + 4];
        acc[0].x = fmaf(xa.x, w.x, acc[0].x); acc[0].y = fmaf(xa.x, w.y, acc[0].y);
        acc[0].z = fmaf(xa.x, w.z, acc[0].z); acc[0].w = fmaf(xa.x, w.w, acc[0].w);
        acc[1].x = fmaf(xa.y, w.x, acc[1].x); acc[1].y = fmaf(xa.y, w.y, acc[1].y);
        acc[1].z = fmaf(xa.y, w.z, acc[1].z); acc[1].w = fmaf(xa.y, w.w, acc[1].w);
        acc[2].x = fmaf(xa.z, w.x, acc[2].x); acc[2].y = fmaf(xa.z, w.y, acc[2].y);
        acc[2].z = fmaf(xa.z, w.z, acc[2].z); acc[2].w = fmaf(xa.z, w.w, acc[2].w);
        acc[3].x = fmaf(xa.w, w.x, acc[3].x); acc[3].y = fmaf(xa.w, w.y, acc[3].y);
        acc[3].z = fmaf(xa.w, w.z, acc[3].z); acc[3].w = fmaf(xa.w, w.w, acc[3].w);
        acc[4].x = fmaf(xb.x, w.x, acc[4].x); acc[4].y = fmaf(xb.x, w.y, acc[4].y);
        acc[4].z = fmaf(xb.x, w.z, acc[4].z); acc[4].w = fmaf(xb.x, w.w, acc[4].w);
        acc[5].x = fmaf(xb.y, w.x, acc[5].x); acc[5].y = fmaf(xb.y, w.y, acc[5].y);
        acc[5].z = fmaf(xb.y, w.z, acc[5].z); acc[5].w = fmaf(xb.y, w.w, acc[5].w);
        acc[6].x = fmaf(xb.z, w.x, acc[6].x); acc[6].y = fmaf(xb.z, w.y, acc[6].y);
        acc[6].z = fmaf(xb.z, w.z, acc[6].z); acc[6].w = fmaf(xb.z, w.w, acc[6].w);
        acc[7].x = fmaf(xb.w, w.x, acc[7].x); acc[7].y = fmaf(xb.w, w.y, acc[7].y);
        acc[7].z = fmaf(xb.w, w.z, acc[7].z); acc[7].w = fmaf(xb.w, w.w, acc[7].w);
    }

    const int j0 = 4 * c;
    float* base = (j0 < 64) ? (xl + j0) : (xr + (j0 - 64));
    #pragma unroll
    for (int u = 0; u < 8; u++) {
        size_t row = nb + g * 8 + u;
        *(float4*)(base + row * 64) = acc[u];
    }
}

// ---------------- aggregation: online softmax over in-edges + self loop ------
__global__ __launch_bounds__(256) void agg_kernel(const float* __restrict__ xl,
                                                  const float* __restrict__ xr,
                                                  const float* __restrict__ attf,
                                                  const float* __restrict__ bf,
                                                  const int* __restrict__ rowptr,
                                                  const int* __restrict__ col,
                                                  float* __restrict__ hout)
{
    const int lane = threadIdx.x & 63;
    const int i = blockIdx.x * 4 + (threadIdx.x >> 6);
    if (i >= NN) return;

    const float a = attf[lane];
    const float r = xr[(size_t)i * 64 + lane];
    const float xli = xl[(size_t)i * 64 + lane];

    float t = xli + r;
    float p = (t > 0.f ? t : 0.2f * t) * a;
    #pragma unroll
    for (int off = 1; off < 64; off <<= 1) p += __shfl_xor(p, off, 64);
    float m = p;
    float denom = 1.f;
    float acc = xli;

    int e0 = rowptr[i], e1 = rowptr[i + 1];
    float xN = 0.f;
    if (e0 < e1) { int s0 = col[e0]; xN = xl[(size_t)s0 * 64 + lane]; }
    for (int e = e0; e < e1; e++) {
        float xsv = xN;
        if (e + 1 < e1) { int s2 = col[e + 1]; xN = xl[(size_t)s2 * 64 + lane]; }
        float tt = xsv + r;
        float pp = (tt > 0.f ? tt : 0.2f * tt) * a;
        #pragma unroll
        for (int off = 1; off < 64; off <<= 1) pp += __shfl_xor(pp, off, 64);
        if (pp > m) {
            float sc = __expf(m - pp);
            denom = denom * sc + 1.f;
            acc = acc * sc + xsv;
            m = pp;
        } else {
            float w = __expf(pp - m);
            denom += w;
            acc += w * xsv;
        }
    }
    float o = acc / denom + bf[lane];
    hout[(size_t)i * 64 + lane] = fmaxf(o, 0.f);
}

// ---------------- readout ----------------
__global__ __launch_bounds__(256) void readout_kernel(const float* __restrict__ h,
                                                      const float* __restrict__ WROf,
                                                      const float* __restrict__ brof,
                                                      void* __restrict__ out,
                                                      const int* __restrict__ flagp)
{
    const int lane = threadIdx.x & 63;
    const int i = blockIdx.x * 4 + (threadIdx.x >> 6);
    if (i >= NN) return;
    const int f = flagp[0];
    float hv = h[(size_t)i * 64 + lane];
    float res = 0.f;
    #pragma unroll
    for (int o = 0; o < OUTD; o++) {
        float p = hv * WROf[o * 64 + lane];
        #pragma unroll
        for (int off = 1; off < 64; off <<= 1) p += __shfl_xor(p, off, 64);
        if (lane == o) res = p + brof[o];
    }
    if (lane < OUTD) {
        if (f) ((bf16*)out)[(size_t)i * OUTD + lane] = __float2bfloat16(res);
        else   ((float*)out)[(size_t)i * OUTD + lane] = res;
    }
}

extern "C" void kernel_launch(void* const* d_in, const int* in_sizes, int n_in,
                              void* d_out, int out_size, void* d_ws, size_t ws_size,
                              hipStream_t stream) {
    const void* x   = d_in[0];
    const int* ei   = (const int*)d_in[1];
    const void* Wl0 = d_in[3];  const void* bl0 = d_in[4];
    const void* Wr0 = d_in[5];  const void* br0 = d_in[6];
    const void* at0 = d_in[7];  const void* b0  = d_in[8];
    const void* Wl1 = d_in[9];  const void* bl1 = d_in[10];
    const void* Wr1 = d_in[11]; const void* br1 = d_in[12];
    const void* at1 = d_in[13]; const void* b1  = d_in[14];
    const void* Wl2 = d_in[15]; const void* bl2 = d_in[16];
    const void* Wr2 = d_in[17]; const void* br2 = d_in[18];
    const void* at2 = d_in[19]; const void* b2  = d_in[20];
    const void* Wro = d_in[21]; const void* bro = d_in[22];

    const int* srcArr = ei;
    const int* dstArr = ei + EE;

    float* wf = (float*)d_ws;
    float* WT0   = wf;                       // 16384
    float* WT1   = wf + 16384;               // 8192
    float* WT2   = wf + 24576;               // 8192
    float* small = wf + 32768;               // 1536
    int*   flag  = (int*)(wf + 34304);       // pad 64
    int*   rowptr = (int*)(wf + 34368);      // 80001 (pad 80128)
    int*   bsums  = (int*)(wf + 34368 + 80128);        // 512
    int*   fill   = (int*)(wf + 34368 + 80128 + 512);  // 80000
    int*   col    = (int*)(wf + 34368 + 80128 + 512 + 80000); // 1280000
    float* xl = wf + 1475008;
    float* xr = xl + (size_t)NN * 64;
    float* hA = xr + (size_t)NN * 64;
    float* hB = hA + (size_t)NN * 64;

    float* biasLR0 = small;        float* biasLR1 = small + 128; float* biasLR2 = small + 256;
    float* attf0 = small + 384;    float* attf1 = small + 448;   float* attf2 = small + 512;
    float* bf0   = small + 576;    float* bf1   = small + 640;   float* bf2   = small + 704;
    float* WROf  = small + 768;    float* brof  = small + 1408;

    detect_kernel<<<dim3(1), dim3(64), 0, stream>>>((const unsigned*)Wl0, flag);

    preconvert<<<dim3(134), dim3(256), 0, stream>>>(
        Wl0, Wr0, Wl1, Wr1, Wl2, Wr2, bl0, br0, bl1, br1, bl2, br2,
        at0, at1, at2, b0, b1, b2, Wro, bro, WT0, WT1, WT2, small, flag);

    hipMemsetAsync(fill, 0, (size_t)NN * 4, stream);
    hist_kernel<<<dim3(EE / 256), dim3(256), 0, stream>>>(dstArr, fill);
    scan1<<<dim3(313), dim3(256), 0, stream>>>(fill, rowptr, bsums);
    scan2<<<dim3(1), dim3(512), 0, stream>>>(bsums, 313);
    scan3<<<dim3(313), dim3(256), 0, stream>>>(rowptr, bsums);
    hipMemcpyAsync(fill, rowptr, (size_t)NN * 4, hipMemcpyDeviceToDevice, stream);
    scatter_kernel<<<dim3(EE / 256), dim3(256), 0, stream>>>(srcArr, dstArr, fill, col);

    lin_fast<128, true><<<dim3(NN / 64), dim3(256), 0, stream>>>(x, WT0, biasLR0, xl, xr, flag);
    agg_kernel<<<dim3(NN / 4), dim3(256), 0, stream>>>(xl, xr, attf0, bf0, rowptr, col, hA);

    lin_fast<64, false><<<dim3(NN / 64), dim3(256), 0, stream>>>(hA, WT1, biasLR1, xl, xr, flag);
    agg_kernel<<<dim3(NN / 4), dim3(256), 0, stream>>>(xl, xr, attf1, bf1, rowptr, col, hB);

    lin_fast<64, false><<<dim3(NN / 64), dim3(256), 0, stream>>>(hB, WT2, biasLR2, xl, xr, flag);
    agg_kernel<<<dim3(NN / 4), dim3(256), 0, stream>>>(xl, xr, attf2, bf2, rowptr, col, hA);

    readout_kernel<<<dim3(NN / 4), dim3(256), 0, stream>>>(hA, WROf, brof, d_out, flag);
}

// Round 4
// 735.090 us; speedup vs baseline: 1.5316x; 1.1211x over previous
//
#include <hip/hip_runtime.h>
#include <hip/hip_bf16.h>

// GATv2 3-layer, N=80000 E=1280000 FIN=128 H=64 OUT=10. fp32 compute.
// Round 4: agg restructured for memory-level parallelism:
//   - 8-wide masked edge groups (8 gathers in flight), interleaved butterflies
//   - fixed softmax baseline (self-loop score, clamp 80) -> no online rescale
//   - readout fused into final agg; scan writes fill directly (no memcpy)

#define NN 80000
#define EE 1280000
#define FIN 128
#define HH 64
#define OUTD 10

typedef __hip_bfloat16 bf16;

__device__ __forceinline__ float ldw(const void* p, int i, int f) {
    return f ? __bfloat162float(((const bf16*)p)[i]) : ((const float*)p)[i];
}

// ---------------- dtype detect ----------------
__global__ void detect_kernel(const unsigned* __restrict__ w, int* __restrict__ flag) {
    int lane = threadIdx.x;
    int big = 0;
    for (int i = lane; i < 2048; i += 64) {
        unsigned u = w[i];
        float a = __uint_as_float(u << 16);
        float b = __uint_as_float(u & 0xffff0000u);
        if (!(fabsf(a) <= 1024.f)) big = 1;
        if (!(fabsf(b) <= 1024.f)) big = 1;
    }
    big = (__ballot(big) != 0ull) ? 1 : 0;
    if (lane == 0) flag[0] = big ? 0 : 1;     // 1 = bf16 storage, 0 = fp32
}

// ---------------- preconvert weights: WT[k*128 + j] ----------------
__global__ void preconvert(
    const void* Wl0, const void* Wr0, const void* Wl1, const void* Wr1,
    const void* Wl2, const void* Wr2,
    const void* bl0, const void* br0, const void* bl1, const void* br1,
    const void* bl2, const void* br2,
    const void* att0, const void* att1, const void* att2,
    const void* b0, const void* b1, const void* b2,
    const void* Wro, const void* bro,
    float* WT0, float* WT1, float* WT2, float* small,
    const int* __restrict__ flagp)
{
    const int f = flagp[0];
    int t = blockIdx.x * 256 + threadIdx.x;
    if (t < 16384) {
        int j = t & 127, k = t >> 7;
        float v = (j < 64) ? ldw(Wl0, j * 128 + k, f) : ldw(Wr0, (j - 64) * 128 + k, f);
        WT0[k * 128 + j] = v;
    } else if (t < 24576) {
        int u = t - 16384; int j = u & 127, k = u >> 7;
        float v = (j < 64) ? ldw(Wl1, j * 64 + k, f) : ldw(Wr1, (j - 64) * 64 + k, f);
        WT1[k * 128 + j] = v;
    } else if (t < 32768) {
        int u = t - 24576; int j = u & 127, k = u >> 7;
        float v = (j < 64) ? ldw(Wl2, j * 64 + k, f) : ldw(Wr2, (j - 64) * 64 + k, f);
        WT2[k * 128 + j] = v;
    } else if (t < 34304) {
        int s = t - 32768;
        const void* BL[3] = { bl0, bl1, bl2 };
        const void* BR[3] = { br0, br1, br2 };
        const void* AT[3] = { att0, att1, att2 };
        const void* BB[3] = { b0, b1, b2 };
        float v = 0.f;
        if (s < 384) {
            int l = s / 128, r = s % 128;
            v = (r < 64) ? ldw(BL[l], r, f) : ldw(BR[l], r - 64, f);
        } else if (s < 576) {
            int q = s - 384; v = ldw(AT[q / 64], q % 64, f);
        } else if (s < 768) {
            int q = s - 576; v = ldw(BB[q / 64], q % 64, f);
        } else if (s < 1408) {
            v = ldw(Wro, s - 768, f);
        } else if (s < 1418) {
            v = ldw(bro, s - 1408, f);
        } else return;
        small[s] = v;
    }
}

// ---------------- CSR build ----------------
__global__ void hist_kernel(const int* __restrict__ dst, int* __restrict__ cnt) {
    int k = blockIdx.x * 256 + threadIdx.x;
    if (k < EE) atomicAdd(&cnt[dst[k]], 1);
}

// fill[i] = exclusive prefix (within block); rowptr[i+1] = inclusive prefix
__global__ void scan1(const int* __restrict__ cnt, int* __restrict__ rowptr,
                      int* __restrict__ bsums, int* __restrict__ fill) {
    __shared__ int sh[256];
    int i = blockIdx.x * 256 + threadIdx.x;
    int tid = threadIdx.x;
    int c = (i < NN) ? cnt[i] : 0;
    sh[tid] = c;
    __syncthreads();
    #pragma unroll
    for (int off = 1; off < 256; off <<= 1) {
        int t = (tid >= off) ? sh[tid - off] : 0;
        __syncthreads();
        sh[tid] += t;
        __syncthreads();
    }
    if (i < NN) { rowptr[i + 1] = sh[tid]; fill[i] = sh[tid] - c; }
    if (tid == 255) bsums[blockIdx.x] = sh[255];
}

__global__ void scan2(int* __restrict__ bsums, int nb) {
    __shared__ int sh[512];
    int t = threadIdx.x;
    sh[t] = (t < nb) ? bsums[t] : 0;
    __syncthreads();
    #pragma unroll
    for (int off = 1; off < 512; off <<= 1) {
        int v = (t >= off) ? sh[t - off] : 0;
        __syncthreads();
        sh[t] += v;
        __syncthreads();
    }
    if (t < nb) bsums[t] = sh[t];
}

__global__ void scan3(int* __restrict__ rowptr, int* __restrict__ fill,
                      const int* __restrict__ bsums) {
    int i = blockIdx.x * 256 + threadIdx.x;
    if (i == 0) rowptr[0] = 0;
    int add = (blockIdx.x == 0) ? 0 : bsums[blockIdx.x - 1];
    if (i < NN) { rowptr[i + 1] += add; fill[i] += add; }
}

__global__ void scatter_kernel(const int* __restrict__ src, const int* __restrict__ dst,
                               int* __restrict__ fill, int* __restrict__ col) {
    int k = blockIdx.x * 256 + threadIdx.x;
    if (k < EE) {
        int d = dst[k];
        int pos = atomicAdd(&fill[d], 1);
        col[pos] = src[k];
    }
}

// ---------------- linear (block=256, 64-node tile, 8x4 reg tile) ----------------
template<int F, bool L0>
__global__ __launch_bounds__(256) void lin_fast(const void* __restrict__ hin_,
                                                const float* __restrict__ WT,
                                                const float* __restrict__ biasLR,
                                                float* __restrict__ xl,
                                                float* __restrict__ xr,
                                                const int* __restrict__ flagp)
{
    constexpr int LDR = 72;
    __shared__ __align__(16) float xs[F * LDR];
    const int t = threadIdx.x;
    const int nb = blockIdx.x * 64;

    if (L0 && flagp[0]) {
        const unsigned* hp = (const unsigned*)hin_;
        for (int idx = t; idx < 64 * (F / 2); idx += 256) {
            int r = idx / (F / 2), c = idx % (F / 2);
            unsigned u = hp[(size_t)(nb + r) * (F / 2) + c];
            xs[(2 * c) * LDR + r]     = __uint_as_float(u << 16);
            xs[(2 * c + 1) * LDR + r] = __uint_as_float(u & 0xffff0000u);
        }
    } else {
        const float* hp = (const float*)hin_;
        for (int idx = t; idx < 64 * F; idx += 256) {
            int r = idx / F, c = idx % F;
            xs[c * LDR + r] = hp[(size_t)(nb + r) * F + c];
        }
    }
    __syncthreads();

    const int c = t & 31;
    const int g = t >> 5;
    const float4* W4 = (const float4*)WT;
    const float4 bias = ((const float4*)biasLR)[c];
    float4 acc[8];
    #pragma unroll
    for (int u = 0; u < 8; u++) acc[u] = bias;

    #pragma unroll 2
    for (int k = 0; k < F; k++) {
        float4 w  = W4[k * 32 + c];
        float4 xa = *(const float4*)&xs[k * LDR + g * 8];
        float4 xb = *(const float4*)&xs[k * LDR + g * 8 + 4];
        acc[0].x = fmaf(xa.x, w.x, acc[0].x); acc[0].y = fmaf(xa.x, w.y, acc[0].y);
        acc[0].z = fmaf(xa.x, w.z, acc[0].z); acc[0].w = fmaf(xa.x, w.w, acc[0].w);
        acc[1].x = fmaf(xa.y, w.x, acc[1].x); acc[1].y = fmaf(xa.y, w.y, acc[1].y);
        acc[1].z = fmaf(xa.y, w.z, acc[1].z); acc[1].w = fmaf(xa.y, w.w, acc[1].w);
        acc[2].x = fmaf(xa.z, w.x, acc[2].x); acc[2].y = fmaf(xa.z, w.y, acc[2].y);
        acc[2].z = fmaf(xa.z, w.z, acc[2].z); acc[2].w = fmaf(xa.z, w.w, acc[2].w);
        acc[3].x = fmaf(xa.w, w.x, acc[3].x); acc[3].y = fmaf(xa.w, w.y, acc[3].y);
        acc[3].z = fmaf(xa.w, w.z, acc[3].z); acc[3].w = fmaf(xa.w, w.w, acc[3].w);
        acc[4].x = fmaf(xb.x, w.x, acc[4].x); acc[4].y = fmaf(xb.x, w.y, acc[4].y);
        acc[4].z = fmaf(xb.x, w.z, acc[4].z); acc[4].w = fmaf(xb.x, w.w, acc[4].w);
        acc[5].x = fmaf(xb.y, w.x, acc[5].x); acc[5].y = fmaf(xb.y, w.y, acc[5].y);
        acc[5].z = fmaf(xb.y, w.z, acc[5].z); acc[5].w = fmaf(xb.y, w.w, acc[5].w);
        acc[6].x = fmaf(xb.z, w.x, acc[6].x); acc[6].y = fmaf(xb.z, w.y, acc[6].y);
        acc[6].z = fmaf(xb.z, w.z, acc[6].z); acc[6].w = fmaf(xb.z, w.w, acc[6].w);
        acc[7].x = fmaf(xb.w, w.x, acc[7].x); acc[7].y = fmaf(xb.w, w.y, acc[7].y);
        acc[7].z = fmaf(xb.w, w.z, acc[7].z); acc[7].w = fmaf(xb.w, w.w, acc[7].w);
    }

    const int j0 = 4 * c;
    float* base = (j0 < 64) ? (xl + j0) : (xr + (j0 - 64));
    #pragma unroll
    for (int u = 0; u < 8; u++) {
        size_t row = nb + g * 8 + u;
        *(float4*)(base + row * 64) = acc[u];
    }
}

// ---------------- aggregation: 8-wide masked groups, fixed baseline ----------------
#define LRELU_P(vk, pk) { float tk = vk + r; pk = (tk > 0.f ? tk : 0.2f * tk) * a; }

template<bool FINAL>
__global__ __launch_bounds__(256) void agg_kernel(const float* __restrict__ xl,
                                                  const float* __restrict__ xr,
                                                  const float* __restrict__ attf,
                                                  const float* __restrict__ bf,
                                                  const int* __restrict__ rowptr,
                                                  const int* __restrict__ col,
                                                  float* __restrict__ hout,
                                                  const float* __restrict__ WROf,
                                                  const float* __restrict__ brof,
                                                  void* __restrict__ out,
                                                  const int* __restrict__ flagp)
{
    const int lane = threadIdx.x & 63;
    int iw = blockIdx.x * 4 + (threadIdx.x >> 6);
    if (iw >= NN) return;
    const int i = __builtin_amdgcn_readfirstlane(iw);

    const float a = attf[lane];
    const float r = xr[(size_t)i * 64 + lane];
    const float xli = xl[(size_t)i * 64 + lane];

    // self-loop: baseline score m0
    float p; LRELU_P(xli, p);
    #pragma unroll
    for (int off = 1; off < 64; off <<= 1) p += __shfl_xor(p, off, 64);
    const float m0 = p;
    float denom = 1.f;
    float acc = xli;

    const int e0 = rowptr[i], e1 = rowptr[i + 1];
    const int n = e1 - e0;
    const int eL = e1 - 1;

    for (int base = 0; base < n; base += 8) {
        const int j = e0 + base;
        int s0 = col[j];
        int s1 = col[min(j + 1, eL)];
        int s2 = col[min(j + 2, eL)];
        int s3 = col[min(j + 3, eL)];
        int s4 = col[min(j + 4, eL)];
        int s5 = col[min(j + 5, eL)];
        int s6 = col[min(j + 6, eL)];
        int s7 = col[min(j + 7, eL)];
        float v0 = xl[(size_t)s0 * 64 + lane];
        float v1 = xl[(size_t)s1 * 64 + lane];
        float v2 = xl[(size_t)s2 * 64 + lane];
        float v3 = xl[(size_t)s3 * 64 + lane];
        float v4 = xl[(size_t)s4 * 64 + lane];
        float v5 = xl[(size_t)s5 * 64 + lane];
        float v6 = xl[(size_t)s6 * 64 + lane];
        float v7 = xl[(size_t)s7 * 64 + lane];

        float p0, p1, p2, p3, p4, p5, p6, p7;
        LRELU_P(v0, p0); LRELU_P(v1, p1); LRELU_P(v2, p2); LRELU_P(v3, p3);
        LRELU_P(v4, p4); LRELU_P(v5, p5); LRELU_P(v6, p6); LRELU_P(v7, p7);

        #pragma unroll
        for (int off = 1; off < 64; off <<= 1) {
            p0 += __shfl_xor(p0, off, 64);
            p1 += __shfl_xor(p1, off, 64);
            p2 += __shfl_xor(p2, off, 64);
            p3 += __shfl_xor(p3, off, 64);
            p4 += __shfl_xor(p4, off, 64);
            p5 += __shfl_xor(p5, off, 64);
            p6 += __shfl_xor(p6, off, 64);
            p7 += __shfl_xor(p7, off, 64);
        }

        float q0 =                __expf(fminf(p0 - m0, 80.f));
        float q1 = (base + 1 < n) ? __expf(fminf(p1 - m0, 80.f)) : 0.f;
        float q2 = (base + 2 < n) ? __expf(fminf(p2 - m0, 80.f)) : 0.f;
        float q3 = (base + 3 < n) ? __expf(fminf(p3 - m0, 80.f)) : 0.f;
        float q4 = (base + 4 < n) ? __expf(fminf(p4 - m0, 80.f)) : 0.f;
        float q5 = (base + 5 < n) ? __expf(fminf(p5 - m0, 80.f)) : 0.f;
        float q6 = (base + 6 < n) ? __expf(fminf(p6 - m0, 80.f)) : 0.f;
        float q7 = (base + 7 < n) ? __expf(fminf(p7 - m0, 80.f)) : 0.f;

        denom += ((q0 + q1) + (q2 + q3)) + ((q4 + q5) + (q6 + q7));
        float s01 = fmaf(q1, v1, q0 * v0);
        float s23 = fmaf(q3, v3, q2 * v2);
        float s45 = fmaf(q5, v5, q4 * v4);
        float s67 = fmaf(q7, v7, q6 * v6);
        acc += (s01 + s23) + (s45 + s67);
    }

    float o = fmaxf(acc / denom + bf[lane], 0.f);

    if (!FINAL) {
        hout[(size_t)i * 64 + lane] = o;
    } else {
        const int f = flagp[0];
        float res = 0.f;
        #pragma unroll
        for (int jo = 0; jo < OUTD; jo++) {
            float pr = o * WROf[jo * 64 + lane];
            #pragma unroll
            for (int off = 1; off < 64; off <<= 1) pr += __shfl_xor(pr, off, 64);
            if (lane == jo) res = pr + brof[jo];
        }
        if (lane < OUTD) {
            if (f) ((bf16*)out)[(size_t)i * OUTD + lane] = __float2bfloat16(res);
            else   ((float*)out)[(size_t)i * OUTD + lane] = res;
        }
    }
}

extern "C" void kernel_launch(void* const* d_in, const int* in_sizes, int n_in,
                              void* d_out, int out_size, void* d_ws, size_t ws_size,
                              hipStream_t stream) {
    const void* x   = d_in[0];
    const int* ei   = (const int*)d_in[1];
    const void* Wl0 = d_in[3];  const void* bl0 = d_in[4];
    const void* Wr0 = d_in[5];  const void* br0 = d_in[6];
    const void* at0 = d_in[7];  const void* b0  = d_in[8];
    const void* Wl1 = d_in[9];  const void* bl1 = d_in[10];
    const void* Wr1 = d_in[11]; const void* br1 = d_in[12];
    const void* at1 = d_in[13]; const void* b1  = d_in[14];
    const void* Wl2 = d_in[15]; const void* bl2 = d_in[16];
    const void* Wr2 = d_in[17]; const void* br2 = d_in[18];
    const void* at2 = d_in[19]; const void* b2  = d_in[20];
    const void* Wro = d_in[21]; const void* bro = d_in[22];

    const int* srcArr = ei;
    const int* dstArr = ei + EE;

    float* wf = (float*)d_ws;
    float* WT0   = wf;                       // 16384
    float* WT1   = wf + 16384;               // 8192
    float* WT2   = wf + 24576;               // 8192
    float* small = wf + 32768;               // 1536
    int*   flag  = (int*)(wf + 34304);       // pad 64
    int*   rowptr = (int*)(wf + 34368);      // 80001 (pad 80128)
    int*   bsums  = (int*)(wf + 34368 + 80128);        // 512
    int*   fill   = (int*)(wf + 34368 + 80128 + 512);  // 80000
    int*   col    = (int*)(wf + 34368 + 80128 + 512 + 80000); // 1280000
    float* xl = wf + 1475008;
    float* xr = xl + (size_t)NN * 64;
    float* hA = xr + (size_t)NN * 64;
    float* hB = hA + (size_t)NN * 64;

    float* biasLR0 = small;        float* biasLR1 = small + 128; float* biasLR2 = small + 256;
    float* attf0 = small + 384;    float* attf1 = small + 448;   float* attf2 = small + 512;
    float* bf0   = small + 576;    float* bf1   = small + 640;   float* bf2   = small + 704;
    float* WROf  = small + 768;    float* brof  = small + 1408;

    detect_kernel<<<dim3(1), dim3(64), 0, stream>>>((const unsigned*)Wl0, flag);

    preconvert<<<dim3(134), dim3(256), 0, stream>>>(
        Wl0, Wr0, Wl1, Wr1, Wl2, Wr2, bl0, br0, bl1, br1, bl2, br2,
        at0, at1, at2, b0, b1, b2, Wro, bro, WT0, WT1, WT2, small, flag);

    hipMemsetAsync(fill, 0, (size_t)NN * 4, stream);
    hist_kernel<<<dim3(EE / 256), dim3(256), 0, stream>>>(dstArr, fill);
    scan1<<<dim3(313), dim3(256), 0, stream>>>(fill, rowptr, bsums, fill);
    scan2<<<dim3(1), dim3(512), 0, stream>>>(bsums, 313);
    scan3<<<dim3(313), dim3(256), 0, stream>>>(rowptr, fill, bsums);
    scatter_kernel<<<dim3(EE / 256), dim3(256), 0, stream>>>(srcArr, dstArr, fill, col);

    lin_fast<128, true><<<dim3(NN / 64), dim3(256), 0, stream>>>(x, WT0, biasLR0, xl, xr, flag);
    agg_kernel<false><<<dim3(NN / 4), dim3(256), 0, stream>>>(xl, xr, attf0, bf0, rowptr, col, hA,
                                                              WROf, brof, d_out, flag);

    lin_fast<64, false><<<dim3(NN / 64), dim3(256), 0, stream>>>(hA, WT1, biasLR1, xl, xr, flag);
    agg_kernel<false><<<dim3(NN / 4), dim3(256), 0, stream>>>(xl, xr, attf1, bf1, rowptr, col, hB,
                                                              WROf, brof, d_out, flag);

    lin_fast<64, false><<<dim3(NN / 64), dim3(256), 0, stream>>>(hB, WT2, biasLR2, xl, xr, flag);
    agg_kernel<true><<<dim3(NN / 4), dim3(256), 0, stream>>>(xl, xr, attf2, bf2, rowptr, col, hA,
                                                             WROf, brof, d_out, flag);
}

// Round 5
// 726.727 us; speedup vs baseline: 1.5492x; 1.0115x over previous
//
#include <hip/hip_runtime.h>
#include <hip/hip_bf16.h>

// GATv2 3-layer, N=80000 E=1280000 FIN=128 H=64 OUT=10. fp32 compute.
// Round 5: butterfly elimination via score/aggregate phase split:
//   - score_kernel: thread=edge, per-lane serial dot over 64 feats (no shuffles),
//     writes {src, raw_score} int2 in dst-sorted order
//   - agg2: per-node wave, per-edge = scalar int2 + 1 gather + exp + fma;
//     m0 baseline = self-loop score (one butterfly per node)
//   - hB dropped (ping-pong hA), readout fused in final agg

#define NN 80000
#define EE 1280000
#define FIN 128
#define HH 64
#define OUTD 10

typedef __hip_bfloat16 bf16;

__device__ __forceinline__ float ldw(const void* p, int i, int f) {
    return f ? __bfloat162float(((const bf16*)p)[i]) : ((const float*)p)[i];
}

// ---------------- dtype detect ----------------
__global__ void detect_kernel(const unsigned* __restrict__ w, int* __restrict__ flag) {
    int lane = threadIdx.x;
    int big = 0;
    for (int i = lane; i < 2048; i += 64) {
        unsigned u = w[i];
        float a = __uint_as_float(u << 16);
        float b = __uint_as_float(u & 0xffff0000u);
        if (!(fabsf(a) <= 1024.f)) big = 1;
        if (!(fabsf(b) <= 1024.f)) big = 1;
    }
    big = (__ballot(big) != 0ull) ? 1 : 0;
    if (lane == 0) flag[0] = big ? 0 : 1;     // 1 = bf16 storage, 0 = fp32
}

// ---------------- preconvert weights: WT[k*128 + j] ----------------
__global__ void preconvert(
    const void* Wl0, const void* Wr0, const void* Wl1, const void* Wr1,
    const void* Wl2, const void* Wr2,
    const void* bl0, const void* br0, const void* bl1, const void* br1,
    const void* bl2, const void* br2,
    const void* att0, const void* att1, const void* att2,
    const void* b0, const void* b1, const void* b2,
    const void* Wro, const void* bro,
    float* WT0, float* WT1, float* WT2, float* small,
    const int* __restrict__ flagp)
{
    const int f = flagp[0];
    int t = blockIdx.x * 256 + threadIdx.x;
    if (t < 16384) {
        int j = t & 127, k = t >> 7;
        float v = (j < 64) ? ldw(Wl0, j * 128 + k, f) : ldw(Wr0, (j - 64) * 128 + k, f);
        WT0[k * 128 + j] = v;
    } else if (t < 24576) {
        int u = t - 16384; int j = u & 127, k = u >> 7;
        float v = (j < 64) ? ldw(Wl1, j * 64 + k, f) : ldw(Wr1, (j - 64) * 64 + k, f);
        WT1[k * 128 + j] = v;
    } else if (t < 32768) {
        int u = t - 24576; int j = u & 127, k = u >> 7;
        float v = (j < 64) ? ldw(Wl2, j * 64 + k, f) : ldw(Wr2, (j - 64) * 64 + k, f);
        WT2[k * 128 + j] = v;
    } else if (t < 34304) {
        int s = t - 32768;
        const void* BL[3] = { bl0, bl1, bl2 };
        const void* BR[3] = { br0, br1, br2 };
        const void* AT[3] = { att0, att1, att2 };
        const void* BB[3] = { b0, b1, b2 };
        float v = 0.f;
        if (s < 384) {
            int l = s / 128, r = s % 128;
            v = (r < 64) ? ldw(BL[l], r, f) : ldw(BR[l], r - 64, f);
        } else if (s < 576) {
            int q = s - 384; v = ldw(AT[q / 64], q % 64, f);
        } else if (s < 768) {
            int q = s - 576; v = ldw(BB[q / 64], q % 64, f);
        } else if (s < 1408) {
            v = ldw(Wro, s - 768, f);
        } else if (s < 1418) {
            v = ldw(bro, s - 1408, f);
        } else return;
        small[s] = v;
    }
}

// ---------------- CSR build ----------------
__global__ void hist_kernel(const int* __restrict__ dst, int* __restrict__ cnt) {
    int k = blockIdx.x * 256 + threadIdx.x;
    if (k < EE) atomicAdd(&cnt[dst[k]], 1);
}

__global__ void scan1(const int* __restrict__ cnt, int* __restrict__ rowptr,
                      int* __restrict__ bsums, int* __restrict__ fill) {
    __shared__ int sh[256];
    int i = blockIdx.x * 256 + threadIdx.x;
    int tid = threadIdx.x;
    int c = (i < NN) ? cnt[i] : 0;
    sh[tid] = c;
    __syncthreads();
    #pragma unroll
    for (int off = 1; off < 256; off <<= 1) {
        int t = (tid >= off) ? sh[tid - off] : 0;
        __syncthreads();
        sh[tid] += t;
        __syncthreads();
    }
    if (i < NN) { rowptr[i + 1] = sh[tid]; fill[i] = sh[tid] - c; }
    if (tid == 255) bsums[blockIdx.x] = sh[255];
}

__global__ void scan2(int* __restrict__ bsums, int nb) {
    __shared__ int sh[512];
    int t = threadIdx.x;
    sh[t] = (t < nb) ? bsums[t] : 0;
    __syncthreads();
    #pragma unroll
    for (int off = 1; off < 512; off <<= 1) {
        int v = (t >= off) ? sh[t - off] : 0;
        __syncthreads();
        sh[t] += v;
        __syncthreads();
    }
    if (t < nb) bsums[t] = sh[t];
}

__global__ void scan3(int* __restrict__ rowptr, int* __restrict__ fill,
                      const int* __restrict__ bsums) {
    int i = blockIdx.x * 256 + threadIdx.x;
    if (i == 0) rowptr[0] = 0;
    int add = (blockIdx.x == 0) ? 0 : bsums[blockIdx.x - 1];
    if (i < NN) { rowptr[i + 1] += add; fill[i] += add; }
}

// scatter writes {src,dst} pairs in dst-sorted order
__global__ void scatter_kernel(const int* __restrict__ src, const int* __restrict__ dst,
                               int* __restrict__ fill, int2* __restrict__ col2) {
    int k = blockIdx.x * 256 + threadIdx.x;
    if (k < EE) {
        int d = dst[k];
        int pos = atomicAdd(&fill[d], 1);
        col2[pos] = make_int2(src[k], d);
    }
}

// ---------------- linear (block=256, 64-node tile, 8x4 reg tile) ----------------
template<int F, bool L0>
__global__ __launch_bounds__(256) void lin_fast(const void* __restrict__ hin_,
                                                const float* __restrict__ WT,
                                                const float* __restrict__ biasLR,
                                                float* __restrict__ xl,
                                                float* __restrict__ xr,
                                                const int* __restrict__ flagp)
{
    constexpr int LDR = 72;
    __shared__ __align__(16) float xs[F * LDR];
    const int t = threadIdx.x;
    const int nb = blockIdx.x * 64;

    if (L0 && flagp[0]) {
        const unsigned* hp = (const unsigned*)hin_;
        for (int idx = t; idx < 64 * (F / 2); idx += 256) {
            int r = idx / (F / 2), c = idx % (F / 2);
            unsigned u = hp[(size_t)(nb + r) * (F / 2) + c];
            xs[(2 * c) * LDR + r]     = __uint_as_float(u << 16);
            xs[(2 * c + 1) * LDR + r] = __uint_as_float(u & 0xffff0000u);
        }
    } else {
        const float* hp = (const float*)hin_;
        for (int idx = t; idx < 64 * F; idx += 256) {
            int r = idx / F, c = idx % F;
            xs[c * LDR + r] = hp[(size_t)(nb + r) * F + c];
        }
    }
    __syncthreads();

    const int c = t & 31;
    const int g = t >> 5;
    const float4* W4 = (const float4*)WT;
    const float4 bias = ((const float4*)biasLR)[c];
    float4 acc[8];
    #pragma unroll
    for (int u = 0; u < 8; u++) acc[u] = bias;

    #pragma unroll 2
    for (int k = 0; k < F; k++) {
        float4 w  = W4[k * 32 + c];
        float4 xa = *(const float4*)&xs[k * LDR + g * 8];
        float4 xb = *(const float4*)&xs[k * LDR + g * 8 + 4];
        acc[0].x = fmaf(xa.x, w.x, acc[0].x); acc[0].y = fmaf(xa.x, w.y, acc[0].y);
        acc[0].z = fmaf(xa.x, w.z, acc[0].z); acc[0].w = fmaf(xa.x, w.w, acc[0].w);
        acc[1].x = fmaf(xa.y, w.x, acc[1].x); acc[1].y = fmaf(xa.y, w.y, acc[1].y);
        acc[1].z = fmaf(xa.y, w.z, acc[1].z); acc[1].w = fmaf(xa.y, w.w, acc[1].w);
        acc[2].x = fmaf(xa.z, w.x, acc[2].x); acc[2].y = fmaf(xa.z, w.y, acc[2].y);
        acc[2].z = fmaf(xa.z, w.z, acc[2].z); acc[2].w = fmaf(xa.z, w.w, acc[2].w);
        acc[3].x = fmaf(xa.w, w.x, acc[3].x); acc[3].y = fmaf(xa.w, w.y, acc[3].y);
        acc[3].z = fmaf(xa.w, w.z, acc[3].z); acc[3].w = fmaf(xa.w, w.w, acc[3].w);
        acc[4].x = fmaf(xb.x, w.x, acc[4].x); acc[4].y = fmaf(xb.x, w.y, acc[4].y);
        acc[4].z = fmaf(xb.x, w.z, acc[4].z); acc[4].w = fmaf(xb.x, w.w, acc[4].w);
        acc[5].x = fmaf(xb.y, w.x, acc[5].x); acc[5].y = fmaf(xb.y, w.y, acc[5].y);
        acc[5].z = fmaf(xb.y, w.z, acc[5].z); acc[5].w = fmaf(xb.y, w.w, acc[5].w);
        acc[6].x = fmaf(xb.z, w.x, acc[6].x); acc[6].y = fmaf(xb.z, w.y, acc[6].y);
        acc[6].z = fmaf(xb.z, w.z, acc[6].z); acc[6].w = fmaf(xb.z, w.w, acc[6].w);
        acc[7].x = fmaf(xb.w, w.x, acc[7].x); acc[7].y = fmaf(xb.w, w.y, acc[7].y);
        acc[7].z = fmaf(xb.w, w.z, acc[7].z); acc[7].w = fmaf(xb.w, w.w, acc[7].w);
    }

    const int j0 = 4 * c;
    float* base = (j0 < 64) ? (xl + j0) : (xr + (j0 - 64));
    #pragma unroll
    for (int u = 0; u < 8; u++) {
        size_t row = nb + g * 8 + u;
        *(float4*)(base + row * 64) = acc[u];
    }
}

// ---------------- score: thread=edge, serial 64-feat dot, no shuffles ----------
__global__ __launch_bounds__(256) void score_kernel(const float* __restrict__ xl,
                                                    const float* __restrict__ xr,
                                                    const float* __restrict__ attf,
                                                    const int2* __restrict__ col2,
                                                    int2* __restrict__ sq)
{
    int j = blockIdx.x * 256 + threadIdx.x;
    if (j >= EE) return;
    int2 sd = col2[j];
    const float4* xlp = (const float4*)(xl + (size_t)sd.x * 64);
    const float4* xrp = (const float4*)(xr + (size_t)sd.y * 64);
    const float4* at4 = (const float4*)attf;
    float acc = 0.f;
    #pragma unroll 4
    for (int c = 0; c < 16; c++) {
        float4 xa = xlp[c], xb = xrp[c], aa = at4[c];
        float u0 = xa.x + xb.x, u1 = xa.y + xb.y, u2 = xa.z + xb.z, u3 = xa.w + xb.w;
        float l0 = fmaf(0.4f, fabsf(u0), 0.6f * u0);
        float l1 = fmaf(0.4f, fabsf(u1), 0.6f * u1);
        float l2 = fmaf(0.4f, fabsf(u2), 0.6f * u2);
        float l3 = fmaf(0.4f, fabsf(u3), 0.6f * u3);
        acc = fmaf(aa.x, l0, acc);
        acc = fmaf(aa.y, l1, acc);
        acc = fmaf(aa.z, l2, acc);
        acc = fmaf(aa.w, l3, acc);
    }
    sq[j] = make_int2(sd.x, __float_as_int(acc));
}

// ---------------- aggregation: per-node wave, precomputed scores ---------------
template<bool FINAL>
__global__ __launch_bounds__(256) void agg2_kernel(const float* __restrict__ xl,
                                                   const float* __restrict__ xr,
                                                   const float* __restrict__ attf,
                                                   const float* __restrict__ bf,
                                                   const int* __restrict__ rowptr,
                                                   const int2* __restrict__ sq,
                                                   float* __restrict__ hout,
                                                   const float* __restrict__ WROf,
                                                   const float* __restrict__ brof,
                                                   void* __restrict__ out,
                                                   const int* __restrict__ flagp)
{
    const int lane = threadIdx.x & 63;
    int iw = blockIdx.x * 4 + (threadIdx.x >> 6);
    if (iw >= NN) return;
    const int i = __builtin_amdgcn_readfirstlane(iw);

    const float a = attf[lane];
    const float r = xr[(size_t)i * 64 + lane];
    const float xli = xl[(size_t)i * 64 + lane];

    // m0 = self-loop score (one butterfly per node)
    float t0 = xli + r;
    float p = fmaf(0.4f, fabsf(t0), 0.6f * t0) * a;
    #pragma unroll
    for (int off = 1; off < 64; off <<= 1) p += __shfl_xor(p, off, 64);
    const float m0 = p;

    float denom = 1.f;
    float acc = xli;

    const int e0 = rowptr[i], e1 = rowptr[i + 1];
    const int n = e1 - e0;
    const int eL = e1 - 1;

    for (int base = 0; base < n; base += 8) {
        const int j = e0 + base;
        int2 q0 = sq[j];
        int2 q1 = sq[min(j + 1, eL)];
        int2 q2 = sq[min(j + 2, eL)];
        int2 q3 = sq[min(j + 3, eL)];
        int2 q4 = sq[min(j + 4, eL)];
        int2 q5 = sq[min(j + 5, eL)];
        int2 q6 = sq[min(j + 6, eL)];
        int2 q7 = sq[min(j + 7, eL)];
        float v0 = xl[(size_t)q0.x * 64 + lane];
        float v1 = xl[(size_t)q1.x * 64 + lane];
        float v2 = xl[(size_t)q2.x * 64 + lane];
        float v3 = xl[(size_t)q3.x * 64 + lane];
        float v4 = xl[(size_t)q4.x * 64 + lane];
        float v5 = xl[(size_t)q5.x * 64 + lane];
        float v6 = xl[(size_t)q6.x * 64 + lane];
        float v7 = xl[(size_t)q7.x * 64 + lane];

        float w0 =                __expf(fminf(__int_as_float(q0.y) - m0, 80.f));
        float w1 = (base + 1 < n) ? __expf(fminf(__int_as_float(q1.y) - m0, 80.f)) : 0.f;
        float w2 = (base + 2 < n) ? __expf(fminf(__int_as_float(q2.y) - m0, 80.f)) : 0.f;
        float w3 = (base + 3 < n) ? __expf(fminf(__int_as_float(q3.y) - m0, 80.f)) : 0.f;
        float w4 = (base + 4 < n) ? __expf(fminf(__int_as_float(q4.y) - m0, 80.f)) : 0.f;
        float w5 = (base + 5 < n) ? __expf(fminf(__int_as_float(q5.y) - m0, 80.f)) : 0.f;
        float w6 = (base + 6 < n) ? __expf(fminf(__int_as_float(q6.y) - m0, 80.f)) : 0.f;
        float w7 = (base + 7 < n) ? __expf(fminf(__int_as_float(q7.y) - m0, 80.f)) : 0.f;

        denom += ((w0 + w1) + (w2 + w3)) + ((w4 + w5) + (w6 + w7));
        float s01 = fmaf(w1, v1, w0 * v0);
        float s23 = fmaf(w3, v3, w2 * v2);
        float s45 = fmaf(w5, v5, w4 * v4);
        float s67 = fmaf(w7, v7, w6 * v6);
        acc += (s01 + s23) + (s45 + s67);
    }

    float o = fmaxf(acc / denom + bf[lane], 0.f);

    if (!FINAL) {
        hout[(size_t)i * 64 + lane] = o;
    } else {
        const int f = flagp[0];
        float res = 0.f;
        #pragma unroll
        for (int jo = 0; jo < OUTD; jo++) {
            float pr = o * WROf[jo * 64 + lane];
            #pragma unroll
            for (int off = 1; off < 64; off <<= 1) pr += __shfl_xor(pr, off, 64);
            if (lane == jo) res = pr + brof[jo];
        }
        if (lane < OUTD) {
            if (f) ((bf16*)out)[(size_t)i * OUTD + lane] = __float2bfloat16(res);
            else   ((float*)out)[(size_t)i * OUTD + lane] = res;
        }
    }
}

extern "C" void kernel_launch(void* const* d_in, const int* in_sizes, int n_in,
                              void* d_out, int out_size, void* d_ws, size_t ws_size,
                              hipStream_t stream) {
    const void* x   = d_in[0];
    const int* ei   = (const int*)d_in[1];
    const void* Wl0 = d_in[3];  const void* bl0 = d_in[4];
    const void* Wr0 = d_in[5];  const void* br0 = d_in[6];
    const void* at0 = d_in[7];  const void* b0  = d_in[8];
    const void* Wl1 = d_in[9];  const void* bl1 = d_in[10];
    const void* Wr1 = d_in[11]; const void* br1 = d_in[12];
    const void* at1 = d_in[13]; const void* b1  = d_in[14];
    const void* Wl2 = d_in[15]; const void* bl2 = d_in[16];
    const void* Wr2 = d_in[17]; const void* br2 = d_in[18];
    const void* at2 = d_in[19]; const void* b2  = d_in[20];
    const void* Wro = d_in[21]; const void* bro = d_in[22];

    const int* srcArr = ei;
    const int* dstArr = ei + EE;

    float* wf = (float*)d_ws;
    float* WT0   = wf;                        // 16384
    float* WT1   = wf + 16384;                // 8192
    float* WT2   = wf + 24576;                // 8192
    float* small = wf + 32768;                // 1536
    int*   flag  = (int*)(wf + 34304);        // pad 64
    int*   rowptr = (int*)(wf + 34368);       // 80001 (pad 80128)
    int*   bsums  = (int*)(wf + 114496);      // 512
    int*   fill   = (int*)(wf + 115008);      // 80000
    int2*  col2   = (int2*)(wf + 195008);     // EE int2 = 2560000 ints
    int2*  sq     = (int2*)(wf + 2755008);    // EE int2 = 2560000 ints
    float* xl = wf + 5315008;                 // 5120000
    float* xr = xl + (size_t)NN * 64;         // 5120000
    float* hA = xr + (size_t)NN * 64;         // 5120000  (ping-pong, no hB)

    float* biasLR0 = small;        float* biasLR1 = small + 128; float* biasLR2 = small + 256;
    float* attf0 = small + 384;    float* attf1 = small + 448;   float* attf2 = small + 512;
    float* bf0   = small + 576;    float* bf1   = small + 640;   float* bf2   = small + 704;
    float* WROf  = small + 768;    float* brof  = small + 1408;

    detect_kernel<<<dim3(1), dim3(64), 0, stream>>>((const unsigned*)Wl0, flag);

    preconvert<<<dim3(134), dim3(256), 0, stream>>>(
        Wl0, Wr0, Wl1, Wr1, Wl2, Wr2, bl0, br0, bl1, br1, bl2, br2,
        at0, at1, at2, b0, b1, b2, Wro, bro, WT0, WT1, WT2, small, flag);

    hipMemsetAsync(fill, 0, (size_t)NN * 4, stream);
    hist_kernel<<<dim3(EE / 256), dim3(256), 0, stream>>>(dstArr, fill);
    scan1<<<dim3(313), dim3(256), 0, stream>>>(fill, rowptr, bsums, fill);
    scan2<<<dim3(1), dim3(512), 0, stream>>>(bsums, 313);
    scan3<<<dim3(313), dim3(256), 0, stream>>>(rowptr, fill, bsums);
    scatter_kernel<<<dim3(EE / 256), dim3(256), 0, stream>>>(srcArr, dstArr, fill, col2);

    // layer 0
    lin_fast<128, true><<<dim3(NN / 64), dim3(256), 0, stream>>>(x, WT0, biasLR0, xl, xr, flag);
    score_kernel<<<dim3(EE / 256), dim3(256), 0, stream>>>(xl, xr, attf0, col2, sq);
    agg2_kernel<false><<<dim3(NN / 4), dim3(256), 0, stream>>>(xl, xr, attf0, bf0, rowptr, sq, hA,
                                                               WROf, brof, d_out, flag);
    // layer 1
    lin_fast<64, false><<<dim3(NN / 64), dim3(256), 0, stream>>>(hA, WT1, biasLR1, xl, xr, flag);
    score_kernel<<<dim3(EE / 256), dim3(256), 0, stream>>>(xl, xr, attf1, col2, sq);
    agg2_kernel<false><<<dim3(NN / 4), dim3(256), 0, stream>>>(xl, xr, attf1, bf1, rowptr, sq, hA,
                                                               WROf, brof, d_out, flag);
    // layer 2
    lin_fast<64, false><<<dim3(NN / 64), dim3(256), 0, stream>>>(hA, WT2, biasLR2, xl, xr, flag);
    score_kernel<<<dim3(EE / 256), dim3(256), 0, stream>>>(xl, xr, attf2, col2, sq);
    agg2_kernel<true><<<dim3(NN / 4), dim3(256), 0, stream>>>(xl, xr, attf2, bf2, rowptr, sq, hA,
                                                              WROf, brof, d_out, flag);
}

// Round 6
// 689.732 us; speedup vs baseline: 1.6323x; 1.0536x over previous
//
#include <hip/hip_runtime.h>
#include <hip/hip_bf16.h>
#include <hip/hip_fp16.h>

// GATv2 3-layer, N=80000 E=1280000 FIN=128 H=64 OUT=10. fp32 compute.
// Round 6: halve gather traffic: xl stored as fp16 (10.24 MB; 128B row
// segments). score reads xl via uint4 (8 halves); agg2 gathers 2B/lane.
// hist/scatter: 4 edges/thread, int4 loads, 4 atomics in flight.

#define NN 80000
#define EE 1280000
#define FIN 128
#define HH 64
#define OUTD 10

typedef __hip_bfloat16 bf16;

__device__ __forceinline__ float ldw(const void* p, int i, int f) {
    return f ? __bfloat162float(((const bf16*)p)[i]) : ((const float*)p)[i];
}

// ---------------- dtype detect ----------------
__global__ void detect_kernel(const unsigned* __restrict__ w, int* __restrict__ flag) {
    int lane = threadIdx.x;
    int big = 0;
    for (int i = lane; i < 2048; i += 64) {
        unsigned u = w[i];
        float a = __uint_as_float(u << 16);
        float b = __uint_as_float(u & 0xffff0000u);
        if (!(fabsf(a) <= 1024.f)) big = 1;
        if (!(fabsf(b) <= 1024.f)) big = 1;
    }
    big = (__ballot(big) != 0ull) ? 1 : 0;
    if (lane == 0) flag[0] = big ? 0 : 1;     // 1 = bf16 storage, 0 = fp32
}

// ---------------- preconvert weights: WT[k*128 + j] ----------------
__global__ void preconvert(
    const void* Wl0, const void* Wr0, const void* Wl1, const void* Wr1,
    const void* Wl2, const void* Wr2,
    const void* bl0, const void* br0, const void* bl1, const void* br1,
    const void* bl2, const void* br2,
    const void* att0, const void* att1, const void* att2,
    const void* b0, const void* b1, const void* b2,
    const void* Wro, const void* bro,
    float* WT0, float* WT1, float* WT2, float* small,
    const int* __restrict__ flagp)
{
    const int f = flagp[0];
    int t = blockIdx.x * 256 + threadIdx.x;
    if (t < 16384) {
        int j = t & 127, k = t >> 7;
        float v = (j < 64) ? ldw(Wl0, j * 128 + k, f) : ldw(Wr0, (j - 64) * 128 + k, f);
        WT0[k * 128 + j] = v;
    } else if (t < 24576) {
        int u = t - 16384; int j = u & 127, k = u >> 7;
        float v = (j < 64) ? ldw(Wl1, j * 64 + k, f) : ldw(Wr1, (j - 64) * 64 + k, f);
        WT1[k * 128 + j] = v;
    } else if (t < 32768) {
        int u = t - 24576; int j = u & 127, k = u >> 7;
        float v = (j < 64) ? ldw(Wl2, j * 64 + k, f) : ldw(Wr2, (j - 64) * 64 + k, f);
        WT2[k * 128 + j] = v;
    } else if (t < 34304) {
        int s = t - 32768;
        const void* BL[3] = { bl0, bl1, bl2 };
        const void* BR[3] = { br0, br1, br2 };
        const void* AT[3] = { att0, att1, att2 };
        const void* BB[3] = { b0, b1, b2 };
        float v = 0.f;
        if (s < 384) {
            int l = s / 128, r = s % 128;
            v = (r < 64) ? ldw(BL[l], r, f) : ldw(BR[l], r - 64, f);
        } else if (s < 576) {
            int q = s - 384; v = ldw(AT[q / 64], q % 64, f);
        } else if (s < 768) {
            int q = s - 576; v = ldw(BB[q / 64], q % 64, f);
        } else if (s < 1408) {
            v = ldw(Wro, s - 768, f);
        } else if (s < 1418) {
            v = ldw(bro, s - 1408, f);
        } else return;
        small[s] = v;
    }
}

// ---------------- CSR build ----------------
__global__ void hist_kernel(const int* __restrict__ dst, int* __restrict__ cnt) {
    int k = (blockIdx.x * 256 + threadIdx.x) * 4;
    if (k < EE) {
        int4 d = *(const int4*)(dst + k);
        atomicAdd(&cnt[d.x], 1);
        atomicAdd(&cnt[d.y], 1);
        atomicAdd(&cnt[d.z], 1);
        atomicAdd(&cnt[d.w], 1);
    }
}

__global__ void scan1(const int* __restrict__ cnt, int* __restrict__ rowptr,
                      int* __restrict__ bsums, int* __restrict__ fill) {
    __shared__ int sh[256];
    int i = blockIdx.x * 256 + threadIdx.x;
    int tid = threadIdx.x;
    int c = (i < NN) ? cnt[i] : 0;
    sh[tid] = c;
    __syncthreads();
    #pragma unroll
    for (int off = 1; off < 256; off <<= 1) {
        int t = (tid >= off) ? sh[tid - off] : 0;
        __syncthreads();
        sh[tid] += t;
        __syncthreads();
    }
    if (i < NN) { rowptr[i + 1] = sh[tid]; fill[i] = sh[tid] - c; }
    if (tid == 255) bsums[blockIdx.x] = sh[255];
}

__global__ void scan2(int* __restrict__ bsums, int nb) {
    __shared__ int sh[512];
    int t = threadIdx.x;
    sh[t] = (t < nb) ? bsums[t] : 0;
    __syncthreads();
    #pragma unroll
    for (int off = 1; off < 512; off <<= 1) {
        int v = (t >= off) ? sh[t - off] : 0;
        __syncthreads();
        sh[t] += v;
        __syncthreads();
    }
    if (t < nb) bsums[t] = sh[t];
}

__global__ void scan3(int* __restrict__ rowptr, int* __restrict__ fill,
                      const int* __restrict__ bsums) {
    int i = blockIdx.x * 256 + threadIdx.x;
    if (i == 0) rowptr[0] = 0;
    int add = (blockIdx.x == 0) ? 0 : bsums[blockIdx.x - 1];
    if (i < NN) { rowptr[i + 1] += add; fill[i] += add; }
}

__global__ void scatter_kernel(const int* __restrict__ src, const int* __restrict__ dst,
                               int* __restrict__ fill, int2* __restrict__ col2) {
    int k = (blockIdx.x * 256 + threadIdx.x) * 4;
    if (k < EE) {
        int4 s = *(const int4*)(src + k);
        int4 d = *(const int4*)(dst + k);
        int p0 = atomicAdd(&fill[d.x], 1);
        int p1 = atomicAdd(&fill[d.y], 1);
        int p2 = atomicAdd(&fill[d.z], 1);
        int p3 = atomicAdd(&fill[d.w], 1);
        col2[p0] = make_int2(s.x, d.x);
        col2[p1] = make_int2(s.y, d.y);
        col2[p2] = make_int2(s.z, d.z);
        col2[p3] = make_int2(s.w, d.w);
    }
}

// ---------------- linear: xl (fp16) | xr (fp32) ----------------
template<int F, bool L0>
__global__ __launch_bounds__(256) void lin_fast(const void* __restrict__ hin_,
                                                const float* __restrict__ WT,
                                                const float* __restrict__ biasLR,
                                                __half* __restrict__ xlh,
                                                float* __restrict__ xr,
                                                const int* __restrict__ flagp)
{
    constexpr int LDR = 72;
    __shared__ __align__(16) float xs[F * LDR];
    const int t = threadIdx.x;
    const int nb = blockIdx.x * 64;

    if (L0 && flagp[0]) {
        const unsigned* hp = (const unsigned*)hin_;
        for (int idx = t; idx < 64 * (F / 2); idx += 256) {
            int r = idx / (F / 2), c = idx % (F / 2);
            unsigned u = hp[(size_t)(nb + r) * (F / 2) + c];
            xs[(2 * c) * LDR + r]     = __uint_as_float(u << 16);
            xs[(2 * c + 1) * LDR + r] = __uint_as_float(u & 0xffff0000u);
        }
    } else {
        const float* hp = (const float*)hin_;
        for (int idx = t; idx < 64 * F; idx += 256) {
            int r = idx / F, c = idx % F;
            xs[c * LDR + r] = hp[(size_t)(nb + r) * F + c];
        }
    }
    __syncthreads();

    const int c = t & 31;
    const int g = t >> 5;
    const float4* W4 = (const float4*)WT;
    const float4 bias = ((const float4*)biasLR)[c];
    float4 acc[8];
    #pragma unroll
    for (int u = 0; u < 8; u++) acc[u] = bias;

    #pragma unroll 2
    for (int k = 0; k < F; k++) {
        float4 w  = W4[k * 32 + c];
        float4 xa = *(const float4*)&xs[k * LDR + g * 8];
        float4 xb = *(const float4*)&xs[k * LDR + g * 8 + 4];
        acc[0].x = fmaf(xa.x, w.x, acc[0].x); acc[0].y = fmaf(xa.x, w.y, acc[0].y);
        acc[0].z = fmaf(xa.x, w.z, acc[0].z); acc[0].w = fmaf(xa.x, w.w, acc[0].w);
        acc[1].x = fmaf(xa.y, w.x, acc[1].x); acc[1].y = fmaf(xa.y, w.y, acc[1].y);
        acc[1].z = fmaf(xa.y, w.z, acc[1].z); acc[1].w = fmaf(xa.y, w.w, acc[1].w);
        acc[2].x = fmaf(xa.z, w.x, acc[2].x); acc[2].y = fmaf(xa.z, w.y, acc[2].y);
        acc[2].z = fmaf(xa.z, w.z, acc[2].z); acc[2].w = fmaf(xa.z, w.w, acc[2].w);
        acc[3].x = fmaf(xa.w, w.x, acc[3].x); acc[3].y = fmaf(xa.w, w.y, acc[3].y);
        acc[3].z = fmaf(xa.w, w.z, acc[3].z); acc[3].w = fmaf(xa.w, w.w, acc[3].w);
        acc[4].x = fmaf(xb.x, w.x, acc[4].x); acc[4].y = fmaf(xb.x, w.y, acc[4].y);
        acc[4].z = fmaf(xb.x, w.z, acc[4].z); acc[4].w = fmaf(xb.x, w.w, acc[4].w);
        acc[5].x = fmaf(xb.y, w.x, acc[5].x); acc[5].y = fmaf(xb.y, w.y, acc[5].y);
        acc[5].z = fmaf(xb.y, w.z, acc[5].z); acc[5].w = fmaf(xb.y, w.w, acc[5].w);
        acc[6].x = fmaf(xb.z, w.x, acc[6].x); acc[6].y = fmaf(xb.z, w.y, acc[6].y);
        acc[6].z = fmaf(xb.z, w.z, acc[6].z); acc[6].w = fmaf(xb.z, w.w, acc[6].w);
        acc[7].x = fmaf(xb.w, w.x, acc[7].x); acc[7].y = fmaf(xb.w, w.y, acc[7].y);
        acc[7].z = fmaf(xb.w, w.z, acc[7].z); acc[7].w = fmaf(xb.w, w.w, acc[7].w);
    }

    const int j0 = 4 * c;
    if (j0 < 64) {
        #pragma unroll
        for (int u = 0; u < 8; u++) {
            size_t row = nb + g * 8 + u;
            __half* xp = xlh + row * 64 + j0;
            *(__half2*)(xp)     = __floats2half2_rn(acc[u].x, acc[u].y);
            *(__half2*)(xp + 2) = __floats2half2_rn(acc[u].z, acc[u].w);
        }
    } else {
        #pragma unroll
        for (int u = 0; u < 8; u++) {
            size_t row = nb + g * 8 + u;
            *(float4*)(xr + row * 64 + (j0 - 64)) = acc[u];
        }
    }
}

// ---------------- score: thread=edge, fp16 xl via uint4, no shuffles ----------
__global__ __launch_bounds__(256) void score_kernel(const __half* __restrict__ xlh,
                                                    const float* __restrict__ xr,
                                                    const float* __restrict__ attf,
                                                    const int2* __restrict__ col2,
                                                    int2* __restrict__ sq)
{
    int j = blockIdx.x * 256 + threadIdx.x;
    if (j >= EE) return;
    int2 sd = col2[j];
    const uint4* xlp = (const uint4*)(xlh + (size_t)sd.x * 64);   // 8 x 16B, 8 halves each
    const float4* xrp = (const float4*)(xr + (size_t)sd.y * 64);
    const float4* at4 = (const float4*)attf;
    float acc = 0.f;
    #pragma unroll 2
    for (int c = 0; c < 8; c++) {
        uint4 u = xlp[c];
        float2 f0 = __half22float2(*(__half2*)&u.x);
        float2 f1 = __half22float2(*(__half2*)&u.y);
        float2 f2 = __half22float2(*(__half2*)&u.z);
        float2 f3 = __half22float2(*(__half2*)&u.w);
        float4 ra = xrp[2 * c], rb = xrp[2 * c + 1];
        float4 aa = at4[2 * c], ab = at4[2 * c + 1];
        float u0 = f0.x + ra.x, u1 = f0.y + ra.y, u2 = f1.x + ra.z, u3 = f1.y + ra.w;
        float u4 = f2.x + rb.x, u5 = f2.y + rb.y, u6 = f3.x + rb.z, u7 = f3.y + rb.w;
        acc = fmaf(aa.x, fmaf(0.4f, fabsf(u0), 0.6f * u0), acc);
        acc = fmaf(aa.y, fmaf(0.4f, fabsf(u1), 0.6f * u1), acc);
        acc = fmaf(aa.z, fmaf(0.4f, fabsf(u2), 0.6f * u2), acc);
        acc = fmaf(aa.w, fmaf(0.4f, fabsf(u3), 0.6f * u3), acc);
        acc = fmaf(ab.x, fmaf(0.4f, fabsf(u4), 0.6f * u4), acc);
        acc = fmaf(ab.y, fmaf(0.4f, fabsf(u5), 0.6f * u5), acc);
        acc = fmaf(ab.z, fmaf(0.4f, fabsf(u6), 0.6f * u6), acc);
        acc = fmaf(ab.w, fmaf(0.4f, fabsf(u7), 0.6f * u7), acc);
    }
    sq[j] = make_int2(sd.x, __float_as_int(acc));
}

// ---------------- aggregation: per-node wave, fp16 gathers ---------------
template<bool FINAL>
__global__ __launch_bounds__(256) void agg2_kernel(const __half* __restrict__ xlh,
                                                   const float* __restrict__ xr,
                                                   const float* __restrict__ attf,
                                                   const float* __restrict__ bf,
                                                   const int* __restrict__ rowptr,
                                                   const int2* __restrict__ sq,
                                                   float* __restrict__ hout,
                                                   const float* __restrict__ WROf,
                                                   const float* __restrict__ brof,
                                                   void* __restrict__ out,
                                                   const int* __restrict__ flagp)
{
    const int lane = threadIdx.x & 63;
    int iw = blockIdx.x * 4 + (threadIdx.x >> 6);
    if (iw >= NN) return;
    const int i = __builtin_amdgcn_readfirstlane(iw);

    const float a = attf[lane];
    const float r = xr[(size_t)i * 64 + lane];
    const float xli = __half2float(xlh[(size_t)i * 64 + lane]);

    // m0 = self-loop score (one butterfly per node)
    float t0 = xli + r;
    float p = fmaf(0.4f, fabsf(t0), 0.6f * t0) * a;
    #pragma unroll
    for (int off = 1; off < 64; off <<= 1) p += __shfl_xor(p, off, 64);
    const float m0 = p;

    float denom = 1.f;
    float acc = xli;

    const int e0 = rowptr[i], e1 = rowptr[i + 1];
    const int n = e1 - e0;
    const int eL = e1 - 1;

    for (int base = 0; base < n; base += 8) {
        const int j = e0 + base;
        int2 q0 = sq[j];
        int2 q1 = sq[min(j + 1, eL)];
        int2 q2 = sq[min(j + 2, eL)];
        int2 q3 = sq[min(j + 3, eL)];
        int2 q4 = sq[min(j + 4, eL)];
        int2 q5 = sq[min(j + 5, eL)];
        int2 q6 = sq[min(j + 6, eL)];
        int2 q7 = sq[min(j + 7, eL)];
        float v0 = __half2float(xlh[(size_t)q0.x * 64 + lane]);
        float v1 = __half2float(xlh[(size_t)q1.x * 64 + lane]);
        float v2 = __half2float(xlh[(size_t)q2.x * 64 + lane]);
        float v3 = __half2float(xlh[(size_t)q3.x * 64 + lane]);
        float v4 = __half2float(xlh[(size_t)q4.x * 64 + lane]);
        float v5 = __half2float(xlh[(size_t)q5.x * 64 + lane]);
        float v6 = __half2float(xlh[(size_t)q6.x * 64 + lane]);
        float v7 = __half2float(xlh[(size_t)q7.x * 64 + lane]);

        float w0 =                __expf(fminf(__int_as_float(q0.y) - m0, 80.f));
        float w1 = (base + 1 < n) ? __expf(fminf(__int_as_float(q1.y) - m0, 80.f)) : 0.f;
        float w2 = (base + 2 < n) ? __expf(fminf(__int_as_float(q2.y) - m0, 80.f)) : 0.f;
        float w3 = (base + 3 < n) ? __expf(fminf(__int_as_float(q3.y) - m0, 80.f)) : 0.f;
        float w4 = (base + 4 < n) ? __expf(fminf(__int_as_float(q4.y) - m0, 80.f)) : 0.f;
        float w5 = (base + 5 < n) ? __expf(fminf(__int_as_float(q5.y) - m0, 80.f)) : 0.f;
        float w6 = (base + 6 < n) ? __expf(fminf(__int_as_float(q6.y) - m0, 80.f)) : 0.f;
        float w7 = (base + 7 < n) ? __expf(fminf(__int_as_float(q7.y) - m0, 80.f)) : 0.f;

        denom += ((w0 + w1) + (w2 + w3)) + ((w4 + w5) + (w6 + w7));
        float s01 = fmaf(w1, v1, w0 * v0);
        float s23 = fmaf(w3, v3, w2 * v2);
        float s45 = fmaf(w5, v5, w4 * v4);
        float s67 = fmaf(w7, v7, w6 * v6);
        acc += (s01 + s23) + (s45 + s67);
    }

    float o = fmaxf(acc / denom + bf[lane], 0.f);

    if (!FINAL) {
        hout[(size_t)i * 64 + lane] = o;
    } else {
        const int f = flagp[0];
        float res = 0.f;
        #pragma unroll
        for (int jo = 0; jo < OUTD; jo++) {
            float pr = o * WROf[jo * 64 + lane];
            #pragma unroll
            for (int off = 1; off < 64; off <<= 1) pr += __shfl_xor(pr, off, 64);
            if (lane == jo) res = pr + brof[jo];
        }
        if (lane < OUTD) {
            if (f) ((bf16*)out)[(size_t)i * OUTD + lane] = __float2bfloat16(res);
            else   ((float*)out)[(size_t)i * OUTD + lane] = res;
        }
    }
}

extern "C" void kernel_launch(void* const* d_in, const int* in_sizes, int n_in,
                              void* d_out, int out_size, void* d_ws, size_t ws_size,
                              hipStream_t stream) {
    const void* x   = d_in[0];
    const int* ei   = (const int*)d_in[1];
    const void* Wl0 = d_in[3];  const void* bl0 = d_in[4];
    const void* Wr0 = d_in[5];  const void* br0 = d_in[6];
    const void* at0 = d_in[7];  const void* b0  = d_in[8];
    const void* Wl1 = d_in[9];  const void* bl1 = d_in[10];
    const void* Wr1 = d_in[11]; const void* br1 = d_in[12];
    const void* at1 = d_in[13]; const void* b1  = d_in[14];
    const void* Wl2 = d_in[15]; const void* bl2 = d_in[16];
    const void* Wr2 = d_in[17]; const void* br2 = d_in[18];
    const void* at2 = d_in[19]; const void* b2  = d_in[20];
    const void* Wro = d_in[21]; const void* bro = d_in[22];

    const int* srcArr = ei;
    const int* dstArr = ei + EE;

    float* wf = (float*)d_ws;
    float* WT0   = wf;                        // 16384
    float* WT1   = wf + 16384;                // 8192
    float* WT2   = wf + 24576;                // 8192
    float* small = wf + 32768;                // 1536
    int*   flag  = (int*)(wf + 34304);        // pad 64
    int*   rowptr = (int*)(wf + 34368);       // 80001 (pad 80128)
    int*   bsums  = (int*)(wf + 114496);      // 512
    int*   fill   = (int*)(wf + 115008);      // 80000
    int2*  col2   = (int2*)(wf + 195008);     // EE int2 = 2560000 ints
    int2*  sq     = (int2*)(wf + 2755008);    // EE int2 = 2560000 ints
    __half* xlh   = (__half*)(wf + 5315008);  // NN*64 halves = 2560000 floats
    float* xr = wf + 7875008;                 // 5120000
    float* hA = xr + (size_t)NN * 64;         // 5120000

    float* biasLR0 = small;        float* biasLR1 = small + 128; float* biasLR2 = small + 256;
    float* attf0 = small + 384;    float* attf1 = small + 448;   float* attf2 = small + 512;
    float* bf0   = small + 576;    float* bf1   = small + 640;   float* bf2   = small + 704;
    float* WROf  = small + 768;    float* brof  = small + 1408;

    detect_kernel<<<dim3(1), dim3(64), 0, stream>>>((const unsigned*)Wl0, flag);

    preconvert<<<dim3(134), dim3(256), 0, stream>>>(
        Wl0, Wr0, Wl1, Wr1, Wl2, Wr2, bl0, br0, bl1, br1, bl2, br2,
        at0, at1, at2, b0, b1, b2, Wro, bro, WT0, WT1, WT2, small, flag);

    hipMemsetAsync(fill, 0, (size_t)NN * 4, stream);
    hist_kernel<<<dim3(EE / 1024), dim3(256), 0, stream>>>(dstArr, fill);
    scan1<<<dim3(313), dim3(256), 0, stream>>>(fill, rowptr, bsums, fill);
    scan2<<<dim3(1), dim3(512), 0, stream>>>(bsums, 313);
    scan3<<<dim3(313), dim3(256), 0, stream>>>(rowptr, fill, bsums);
    scatter_kernel<<<dim3(EE / 1024), dim3(256), 0, stream>>>(srcArr, dstArr, fill, col2);

    // layer 0
    lin_fast<128, true><<<dim3(NN / 64), dim3(256), 0, stream>>>(x, WT0, biasLR0, xlh, xr, flag);
    score_kernel<<<dim3(EE / 256), dim3(256), 0, stream>>>(xlh, xr, attf0, col2, sq);
    agg2_kernel<false><<<dim3(NN / 4), dim3(256), 0, stream>>>(xlh, xr, attf0, bf0, rowptr, sq, hA,
                                                               WROf, brof, d_out, flag);
    // layer 1
    lin_fast<64, false><<<dim3(NN / 64), dim3(256), 0, stream>>>(hA, WT1, biasLR1, xlh, xr, flag);
    score_kernel<<<dim3(EE / 256), dim3(256), 0, stream>>>(xlh, xr, attf1, col2, sq);
    agg2_kernel<false><<<dim3(NN / 4), dim3(256), 0, stream>>>(xlh, xr, attf1, bf1, rowptr, sq, hA,
                                                               WROf, brof, d_out, flag);
    // layer 2
    lin_fast<64, false><<<dim3(NN / 64), dim3(256), 0, stream>>>(hA, WT2, biasLR2, xlh, xr, flag);
    score_kernel<<<dim3(EE / 256), dim3(256), 0, stream>>>(xlh, xr, attf2, col2, sq);
    agg2_kernel<true><<<dim3(NN / 4), dim3(256), 0, stream>>>(xlh, xr, attf2, bf2, rowptr, sq, hA,
                                                              WROf, brof, d_out, flag);
}

// Round 8
// 594.769 us; speedup vs baseline: 1.8929x; 1.1597x over previous
//
#include <hip/hip_runtime.h>
#include <hip/hip_bf16.h>
#include <hip/hip_fp16.h>

// GATv2 3-layer, N=80000 E=1280000 FIN=128 H=64 OUT=10. fp32 compute.
// Round 8: deterministic locality partition (round-7's replay divergence was a
// timing-dependent edge corruption; only cross-block atomic was the bucket_fill
// reservation). Now: chunk-hist -> per-bucket chunk scan -> bucket scan ->
// deterministic partition (no global atomics) -> per-bucket LDS hist/scatter.
// agg2: 16-wide edge groups; readout fused; xl fp16.

#define NN 80000
#define EE 1280000
#define FIN 128
#define HH 64
#define OUTD 10
#define NBUK 79            // dst>>10 buckets (79*1024 >= 80000)
#define PCH 2048           // edges per partition chunk
#define NCH 625            // EE / PCH

typedef __hip_bfloat16 bf16;

__device__ __forceinline__ float ldw(const void* p, int i, int f) {
    return f ? __bfloat162float(((const bf16*)p)[i]) : ((const float*)p)[i];
}

// ---------------- dtype detect ----------------
__global__ void detect_kernel(const unsigned* __restrict__ w, int* __restrict__ flag) {
    int lane = threadIdx.x;
    int big = 0;
    for (int i = lane; i < 2048; i += 64) {
        unsigned u = w[i];
        float a = __uint_as_float(u << 16);
        float b = __uint_as_float(u & 0xffff0000u);
        if (!(fabsf(a) <= 1024.f)) big = 1;
        if (!(fabsf(b) <= 1024.f)) big = 1;
    }
    big = (__ballot(big) != 0ull) ? 1 : 0;
    if (lane == 0) flag[0] = big ? 0 : 1;     // 1 = bf16 storage, 0 = fp32
}

// ---------------- preconvert weights: WT[k*128 + j] ----------------
__global__ void preconvert(
    const void* Wl0, const void* Wr0, const void* Wl1, const void* Wr1,
    const void* Wl2, const void* Wr2,
    const void* bl0, const void* br0, const void* bl1, const void* br1,
    const void* bl2, const void* br2,
    const void* att0, const void* att1, const void* att2,
    const void* b0, const void* b1, const void* b2,
    const void* Wro, const void* bro,
    float* WT0, float* WT1, float* WT2, float* small,
    const int* __restrict__ flagp)
{
    const int f = flagp[0];
    int t = blockIdx.x * 256 + threadIdx.x;
    if (t < 16384) {
        int j = t & 127, k = t >> 7;
        float v = (j < 64) ? ldw(Wl0, j * 128 + k, f) : ldw(Wr0, (j - 64) * 128 + k, f);
        WT0[k * 128 + j] = v;
    } else if (t < 24576) {
        int u = t - 16384; int j = u & 127, k = u >> 7;
        float v = (j < 64) ? ldw(Wl1, j * 64 + k, f) : ldw(Wr1, (j - 64) * 64 + k, f);
        WT1[k * 128 + j] = v;
    } else if (t < 32768) {
        int u = t - 24576; int j = u & 127, k = u >> 7;
        float v = (j < 64) ? ldw(Wl2, j * 64 + k, f) : ldw(Wr2, (j - 64) * 64 + k, f);
        WT2[k * 128 + j] = v;
    } else if (t < 34304) {
        int s = t - 32768;
        const void* BL[3] = { bl0, bl1, bl2 };
        const void* BR[3] = { br0, br1, br2 };
        const void* AT[3] = { att0, att1, att2 };
        const void* BB[3] = { b0, b1, b2 };
        float v = 0.f;
        if (s < 384) {
            int l = s / 128, r = s % 128;
            v = (r < 64) ? ldw(BL[l], r, f) : ldw(BR[l], r - 64, f);
        } else if (s < 576) {
            int q = s - 384; v = ldw(AT[q / 64], q % 64, f);
        } else if (s < 768) {
            int q = s - 576; v = ldw(BB[q / 64], q % 64, f);
        } else if (s < 1408) {
            v = ldw(Wro, s - 768, f);
        } else if (s < 1418) {
            v = ldw(bro, s - 1408, f);
        } else return;
        small[s] = v;
    }
}

// ---------------- A: per-chunk bucket histogram (no global atomics) ---------
__global__ __launch_bounds__(256) void chunkhist_kernel(const int* __restrict__ dst,
                                                        int* __restrict__ chunkcnt)
{
    __shared__ int h[NBUK];
    const int tid = threadIdx.x, c = blockIdx.x;
    for (int i = tid; i < NBUK; i += 256) h[i] = 0;
    __syncthreads();
    const int e0 = c * PCH + tid * 8;
    int4 a = *(const int4*)(dst + e0);
    int4 b = *(const int4*)(dst + e0 + 4);
    atomicAdd(&h[a.x >> 10], 1); atomicAdd(&h[a.y >> 10], 1);
    atomicAdd(&h[a.z >> 10], 1); atomicAdd(&h[a.w >> 10], 1);
    atomicAdd(&h[b.x >> 10], 1); atomicAdd(&h[b.y >> 10], 1);
    atomicAdd(&h[b.z >> 10], 1); atomicAdd(&h[b.w >> 10], 1);
    __syncthreads();
    for (int i = tid; i < NBUK; i += 256) chunkcnt[i * NCH + c] = h[i];
}

// ---------------- B1: per-bucket exclusive scan over its NCH chunk counts ---
__global__ __launch_bounds__(1024) void cscan_kernel(int* __restrict__ chunkcnt,
                                                     int* __restrict__ bucket_cnt)
{
    __shared__ int s[1024];
    const int b = blockIdx.x, t = threadIdx.x;
    int v = (t < NCH) ? chunkcnt[b * NCH + t] : 0;
    s[t] = v;
    __syncthreads();
    #pragma unroll
    for (int off = 1; off < 1024; off <<= 1) {
        int u = (t >= off) ? s[t - off] : 0;
        __syncthreads();
        s[t] += u;
        __syncthreads();
    }
    if (t < NCH) chunkcnt[b * NCH + t] = s[t] - v;   // exclusive prefix
    if (t == NCH - 1) bucket_cnt[b] = s[t];          // bucket total
}

// ---------------- B2: scan buckets -> bucket_base ----------------
__global__ void bscan_kernel(const int* __restrict__ bucket_cnt,
                             int* __restrict__ bucket_base)
{
    __shared__ int sc[128];
    const int t = threadIdx.x;
    sc[t] = (t < NBUK) ? bucket_cnt[t] : 0;
    __syncthreads();
    #pragma unroll
    for (int off = 1; off < 128; off <<= 1) {
        int v = (t >= off) ? sc[t - off] : 0;
        __syncthreads();
        sc[t] += v;
        __syncthreads();
    }
    if (t < NBUK) bucket_base[t] = (t == 0) ? 0 : sc[t - 1];
    if (t == 0) bucket_base[NBUK] = sc[NBUK - 1];
}

// ---------------- C: deterministic partition into buckets -------------------
__global__ __launch_bounds__(256) void part_kernel(const int* __restrict__ src,
                                                   const int* __restrict__ dst,
                                                   const int* __restrict__ chunkcnt,
                                                   const int* __restrict__ bucket_base,
                                                   int2* __restrict__ part)
{
    __shared__ int hcnt[NBUK];
    __shared__ int sc[128];
    __shared__ int hbase[NBUK + 1];
    __shared__ int hpos[NBUK];
    __shared__ int hgb[NBUK];
    __shared__ int2 stage[PCH];
    const int tid = threadIdx.x, c = blockIdx.x;

    for (int i = tid; i < NBUK; i += 256) hcnt[i] = 0;
    __syncthreads();

    const int e0 = c * PCH + tid * 8;
    int4 sa = *(const int4*)(src + e0);
    int4 sb = *(const int4*)(src + e0 + 4);
    int4 da = *(const int4*)(dst + e0);
    int4 db = *(const int4*)(dst + e0 + 4);
    int dv[8] = { da.x, da.y, da.z, da.w, db.x, db.y, db.z, db.w };
    int sv[8] = { sa.x, sa.y, sa.z, sa.w, sb.x, sb.y, sb.z, sb.w };
    #pragma unroll
    for (int u = 0; u < 8; u++) atomicAdd(&hcnt[dv[u] >> 10], 1);
    __syncthreads();

    if (tid < 128) sc[tid] = (tid < NBUK) ? hcnt[tid] : 0;
    __syncthreads();
    #pragma unroll
    for (int off = 1; off < 128; off <<= 1) {
        int v = (tid < 128 && tid >= off) ? sc[tid - off] : 0;
        __syncthreads();
        if (tid < 128) sc[tid] += v;
        __syncthreads();
    }
    if (tid < NBUK) {
        int b = (tid == 0) ? 0 : sc[tid - 1];
        hbase[tid] = b;
        hpos[tid] = b;
        hgb[tid] = bucket_base[tid] + chunkcnt[tid * NCH + c];  // deterministic base
    }
    if (tid == 0) hbase[NBUK] = PCH;
    __syncthreads();

    #pragma unroll
    for (int u = 0; u < 8; u++) {
        int p = atomicAdd(&hpos[dv[u] >> 10], 1);
        stage[p] = make_int2(sv[u], dv[u]);
    }
    __syncthreads();

    for (int s = tid; s < PCH; s += 256) {
        int lo = 0, hi = NBUK;
        #pragma unroll
        for (int it = 0; it < 7; it++) {
            int mid = (lo + hi) >> 1;
            if (hbase[mid] <= s) lo = mid; else hi = mid;
        }
        part[hgb[lo] + (s - hbase[lo])] = stage[s];
    }
}

// ---------------- fine hist: one block per bucket, LDS counters -------------
__global__ __launch_bounds__(256) void hist_part_kernel(const int2* __restrict__ part,
                                                        const int* __restrict__ bucket_base,
                                                        int* __restrict__ cnt)
{
    __shared__ int lcnt[1024];
    const int b = blockIdx.x, tid = threadIdx.x;
    const int dbase = b << 10;
    for (int i = tid; i < 1024; i += 256) lcnt[i] = 0;
    __syncthreads();
    const int eb = bucket_base[b], ee = bucket_base[b + 1];
    for (int e = eb + tid; e < ee; e += 256)
        atomicAdd(&lcnt[part[e].y - dbase], 1);
    __syncthreads();
    const int nd = min(1024, NN - dbase);
    for (int i = tid; i < nd; i += 256) cnt[dbase + i] = lcnt[i];
}

// ---------------- scans ----------------
__global__ void scan1(const int* __restrict__ cnt, int* __restrict__ rowptr,
                      int* __restrict__ bsums) {
    __shared__ int sh[256];
    int i = blockIdx.x * 256 + threadIdx.x;
    int tid = threadIdx.x;
    int c = (i < NN) ? cnt[i] : 0;
    sh[tid] = c;
    __syncthreads();
    #pragma unroll
    for (int off = 1; off < 256; off <<= 1) {
        int t = (tid >= off) ? sh[tid - off] : 0;
        __syncthreads();
        sh[tid] += t;
        __syncthreads();
    }
    if (i < NN) rowptr[i + 1] = sh[tid];
    if (tid == 255) bsums[blockIdx.x] = sh[255];
}

__global__ void scan2(int* __restrict__ bsums, int nb) {
    __shared__ int sh[512];
    int t = threadIdx.x;
    sh[t] = (t < nb) ? bsums[t] : 0;
    __syncthreads();
    #pragma unroll
    for (int off = 1; off < 512; off <<= 1) {
        int v = (t >= off) ? sh[t - off] : 0;
        __syncthreads();
        sh[t] += v;
        __syncthreads();
    }
    if (t < nb) bsums[t] = sh[t];
}

__global__ void scan3(int* __restrict__ rowptr, const int* __restrict__ bsums) {
    int i = blockIdx.x * 256 + threadIdx.x;
    if (i == 0) rowptr[0] = 0;
    int add = (blockIdx.x == 0) ? 0 : bsums[blockIdx.x - 1];
    if (i < NN) rowptr[i + 1] += add;
}

// ---------------- P2: fine scatter, one block per bucket --------------------
__global__ __launch_bounds__(256) void scatter2_kernel(const int2* __restrict__ part,
                                                       const int* __restrict__ bucket_base,
                                                       const int* __restrict__ rowptr,
                                                       int2* __restrict__ col2)
{
    __shared__ int lfill[1024];
    const int b = blockIdx.x, tid = threadIdx.x;
    const int dbase = b << 10;
    const int nd = min(1024, NN - dbase);
    for (int i = tid; i < nd; i += 256) lfill[i] = rowptr[dbase + i];
    __syncthreads();
    const int eb = bucket_base[b], ee = bucket_base[b + 1];
    for (int e = eb + tid; e < ee; e += 256) {
        int2 sd = part[e];
        int pos = atomicAdd(&lfill[sd.y - dbase], 1);
        col2[pos] = sd;
    }
}

// ---------------- linear: xl (fp16) | xr (fp32) ----------------
template<int F, bool L0>
__global__ __launch_bounds__(256) void lin_fast(const void* __restrict__ hin_,
                                                const float* __restrict__ WT,
                                                const float* __restrict__ biasLR,
                                                __half* __restrict__ xlh,
                                                float* __restrict__ xr,
                                                const int* __restrict__ flagp)
{
    constexpr int LDR = 72;
    __shared__ __align__(16) float xs[F * LDR];
    const int t = threadIdx.x;
    const int nb = blockIdx.x * 64;

    if (L0 && flagp[0]) {
        const unsigned* hp = (const unsigned*)hin_;
        for (int idx = t; idx < 64 * (F / 2); idx += 256) {
            int r = idx / (F / 2), c = idx % (F / 2);
            unsigned u = hp[(size_t)(nb + r) * (F / 2) + c];
            xs[(2 * c) * LDR + r]     = __uint_as_float(u << 16);
            xs[(2 * c + 1) * LDR + r] = __uint_as_float(u & 0xffff0000u);
        }
    } else {
        const float* hp = (const float*)hin_;
        for (int idx = t; idx < 64 * F; idx += 256) {
            int r = idx / F, c = idx % F;
            xs[c * LDR + r] = hp[(size_t)(nb + r) * F + c];
        }
    }
    __syncthreads();

    const int c = t & 31;
    const int g = t >> 5;
    const float4* W4 = (const float4*)WT;
    const float4 bias = ((const float4*)biasLR)[c];
    float4 acc[8];
    #pragma unroll
    for (int u = 0; u < 8; u++) acc[u] = bias;

    #pragma unroll 2
    for (int k = 0; k < F; k++) {
        float4 w  = W4[k * 32 + c];
        float4 xa = *(const float4*)&xs[k * LDR + g * 8];
        float4 xb = *(const float4*)&xs[k * LDR + g * 8 + 4];
        acc[0].x = fmaf(xa.x, w.x, acc[0].x); acc[0].y = fmaf(xa.x, w.y, acc[0].y);
        acc[0].z = fmaf(xa.x, w.z, acc[0].z); acc[0].w = fmaf(xa.x, w.w, acc[0].w);
        acc[1].x = fmaf(xa.y, w.x, acc[1].x); acc[1].y = fmaf(xa.y, w.y, acc[1].y);
        acc[1].z = fmaf(xa.y, w.z, acc[1].z); acc[1].w = fmaf(xa.y, w.w, acc[1].w);
        acc[2].x = fmaf(xa.z, w.x, acc[2].x); acc[2].y = fmaf(xa.z, w.y, acc[2].y);
        acc[2].z = fmaf(xa.z, w.z, acc[2].z); acc[2].w = fmaf(xa.z, w.w, acc[2].w);
        acc[3].x = fmaf(xa.w, w.x, acc[3].x); acc[3].y = fmaf(xa.w, w.y, acc[3].y);
        acc[3].z = fmaf(xa.w, w.z, acc[3].z); acc[3].w = fmaf(xa.w, w.w, acc[3].w);
        acc[4].x = fmaf(xb.x, w.x, acc[4].x); acc[4].y = fmaf(xb.x, w.y, acc[4].y);
        acc[4].z = fmaf(xb.x, w.z, acc[4].z); acc[4].w = fmaf(xb.x, w.w, acc[4].w);
        acc[5].x = fmaf(xb.y, w.x, acc[5].x); acc[5].y = fmaf(xb.y, w.y, acc[5].y);
        acc[5].z = fmaf(xb.y, w.z, acc[5].z); acc[5].w = fmaf(xb.y, w.w, acc[5].w);
        acc[6].x = fmaf(xb.z, w.x, acc[6].x); acc[6].y = fmaf(xb.z, w.y, acc[6].y);
        acc[6].z = fmaf(xb.z, w.z, acc[6].z); acc[6].w = fmaf(xb.z, w.w, acc[6].w);
        acc[7].x = fmaf(xb.w, w.x, acc[7].x); acc[7].y = fmaf(xb.w, w.y, acc[7].y);
        acc[7].z = fmaf(xb.w, w.z, acc[7].z); acc[7].w = fmaf(xb.w, w.w, acc[7].w);
    }

    const int j0 = 4 * c;
    if (j0 < 64) {
        #pragma unroll
        for (int u = 0; u < 8; u++) {
            size_t row = nb + g * 8 + u;
            __half* xp = xlh + row * 64 + j0;
            *(__half2*)(xp)     = __floats2half2_rn(acc[u].x, acc[u].y);
            *(__half2*)(xp + 2) = __floats2half2_rn(acc[u].z, acc[u].w);
        }
    } else {
        #pragma unroll
        for (int u = 0; u < 8; u++) {
            size_t row = nb + g * 8 + u;
            *(float4*)(xr + row * 64 + (j0 - 64)) = acc[u];
        }
    }
}

// ---------------- score: thread=edge, fp16 xl via uint4, no shuffles ----------
__global__ __launch_bounds__(256) void score_kernel(const __half* __restrict__ xlh,
                                                    const float* __restrict__ xr,
                                                    const float* __restrict__ attf,
                                                    const int2* __restrict__ col2,
                                                    int2* __restrict__ sq)
{
    int j = blockIdx.x * 256 + threadIdx.x;
    if (j >= EE) return;
    int2 sd = col2[j];
    const uint4* xlp = (const uint4*)(xlh + (size_t)sd.x * 64);
    const float4* xrp = (const float4*)(xr + (size_t)sd.y * 64);
    const float4* at4 = (const float4*)attf;
    float acc = 0.f;
    #pragma unroll 2
    for (int c = 0; c < 8; c++) {
        uint4 u = xlp[c];
        float2 f0 = __half22float2(*(__half2*)&u.x);
        float2 f1 = __half22float2(*(__half2*)&u.y);
        float2 f2 = __half22float2(*(__half2*)&u.z);
        float2 f3 = __half22float2(*(__half2*)&u.w);
        float4 ra = xrp[2 * c], rb = xrp[2 * c + 1];
        float4 aa = at4[2 * c], ab = at4[2 * c + 1];
        float u0 = f0.x + ra.x, u1 = f0.y + ra.y, u2 = f1.x + ra.z, u3 = f1.y + ra.w;
        float u4 = f2.x + rb.x, u5 = f2.y + rb.y, u6 = f3.x + rb.z, u7 = f3.y + rb.w;
        acc = fmaf(aa.x, fmaf(0.4f, fabsf(u0), 0.6f * u0), acc);
        acc = fmaf(aa.y, fmaf(0.4f, fabsf(u1), 0.6f * u1), acc);
        acc = fmaf(aa.z, fmaf(0.4f, fabsf(u2), 0.6f * u2), acc);
        acc = fmaf(aa.w, fmaf(0.4f, fabsf(u3), 0.6f * u3), acc);
        acc = fmaf(ab.x, fmaf(0.4f, fabsf(u4), 0.6f * u4), acc);
        acc = fmaf(ab.y, fmaf(0.4f, fabsf(u5), 0.6f * u5), acc);
        acc = fmaf(ab.z, fmaf(0.4f, fabsf(u6), 0.6f * u6), acc);
        acc = fmaf(ab.w, fmaf(0.4f, fabsf(u7), 0.6f * u7), acc);
    }
    sq[j] = make_int2(sd.x, __float_as_int(acc));
}

// ---------------- aggregation: per-node wave, 16-wide groups ---------------
template<bool FINAL>
__global__ __launch_bounds__(256) void agg2_kernel(const __half* __restrict__ xlh,
                                                   const float* __restrict__ xr,
                                                   const float* __restrict__ attf,
                                                   const float* __restrict__ bf,
                                                   const int* __restrict__ rowptr,
                                                   const int2* __restrict__ sq,
                                                   float* __restrict__ hout,
                                                   const float* __restrict__ WROf,
                                                   const float* __restrict__ brof,
                                                   void* __restrict__ out,
                                                   const int* __restrict__ flagp)
{
    const int lane = threadIdx.x & 63;
    int iw = blockIdx.x * 4 + (threadIdx.x >> 6);
    if (iw >= NN) return;
    const int i = __builtin_amdgcn_readfirstlane(iw);

    const float a = attf[lane];
    const float r = xr[(size_t)i * 64 + lane];
    const float xli = __half2float(xlh[(size_t)i * 64 + lane]);

    float t0 = xli + r;
    float p = fmaf(0.4f, fabsf(t0), 0.6f * t0) * a;
    #pragma unroll
    for (int off = 1; off < 64; off <<= 1) p += __shfl_xor(p, off, 64);
    const float m0 = p;

    float denom = 1.f;
    float acc = xli;

    const int e0 = rowptr[i], e1 = rowptr[i + 1];
    const int n = e1 - e0;
    const int eL = e1 - 1;

    for (int base = 0; base < n; base += 16) {
        const int j = e0 + base;
        int2 q[16];
        #pragma unroll
        for (int u = 0; u < 16; u++) q[u] = sq[min(j + u, eL)];
        float v[16];
        #pragma unroll
        for (int u = 0; u < 16; u++) v[u] = __half2float(xlh[(size_t)q[u].x * 64 + lane]);
        float w[16];
        #pragma unroll
        for (int u = 0; u < 16; u++)
            w[u] = (base + u < n) ? __expf(fminf(__int_as_float(q[u].y) - m0, 80.f)) : 0.f;

        float d01 = 0.f, d23 = 0.f;
        float a01 = 0.f, a23 = 0.f;
        #pragma unroll
        for (int u = 0; u < 8; u++) {
            d01 += w[u]; d23 += w[u + 8];
            a01 = fmaf(w[u], v[u], a01);
            a23 = fmaf(w[u + 8], v[u + 8], a23);
        }
        denom += d01 + d23;
        acc += a01 + a23;
    }

    float o = fmaxf(acc / denom + bf[lane], 0.f);

    if (!FINAL) {
        hout[(size_t)i * 64 + lane] = o;
    } else {
        const int f = flagp[0];
        float res = 0.f;
        #pragma unroll
        for (int jo = 0; jo < OUTD; jo++) {
            float pr = o * WROf[jo * 64 + lane];
            #pragma unroll
            for (int off = 1; off < 64; off <<= 1) pr += __shfl_xor(pr, off, 64);
            if (lane == jo) res = pr + brof[jo];
        }
        if (lane < OUTD) {
            if (f) ((bf16*)out)[(size_t)i * OUTD + lane] = __float2bfloat16(res);
            else   ((float*)out)[(size_t)i * OUTD + lane] = res;
        }
    }
}

extern "C" void kernel_launch(void* const* d_in, const int* in_sizes, int n_in,
                              void* d_out, int out_size, void* d_ws, size_t ws_size,
                              hipStream_t stream) {
    const void* x   = d_in[0];
    const int* ei   = (const int*)d_in[1];
    const void* Wl0 = d_in[3];  const void* bl0 = d_in[4];
    const void* Wr0 = d_in[5];  const void* br0 = d_in[6];
    const void* at0 = d_in[7];  const void* b0  = d_in[8];
    const void* Wl1 = d_in[9];  const void* bl1 = d_in[10];
    const void* Wr1 = d_in[11]; const void* br1 = d_in[12];
    const void* at1 = d_in[13]; const void* b1  = d_in[14];
    const void* Wl2 = d_in[15]; const void* bl2 = d_in[16];
    const void* Wr2 = d_in[17]; const void* br2 = d_in[18];
    const void* at2 = d_in[19]; const void* b2  = d_in[20];
    const void* Wro = d_in[21]; const void* bro = d_in[22];

    const int* srcArr = ei;
    const int* dstArr = ei + EE;

    float* wf = (float*)d_ws;
    float* WT0   = wf;                        // 16384
    float* WT1   = wf + 16384;                // 8192
    float* WT2   = wf + 24576;                // 8192
    float* small = wf + 32768;                // 1536
    int*   flag  = (int*)(wf + 34304);        // pad 64
    int*   rowptr = (int*)(wf + 34368);       // 80001 (pad 80128)
    int*   bsums  = (int*)(wf + 114496);      // 512
    int*   fillc  = (int*)(wf + 115008);      // 80000 (per-dst counts)
    int*   bucket_cnt  = (int*)(wf + 195008); // 128
    int*   bucket_base = (int*)(wf + 195136); // 128 (+1 used)
    int*   chunkcnt    = (int*)(wf + 195264); // NBUK*NCH = 49375 (pad 49472)
    int2*  part   = (int2*)(wf + 244736);     // EE int2 = 2560000 ints
    int2*  col2   = (int2*)(wf + 2804736);    // 2560000
    int2*  sq     = (int2*)(wf + 5364736);    // 2560000
    __half* xlh   = (__half*)(wf + 7924736);  // NN*64 halves = 2560000 ints
    float* xr = wf + 10484736;                // 5120000
    float* hA = xr + (size_t)NN * 64;         // 5120000

    float* biasLR0 = small;        float* biasLR1 = small + 128; float* biasLR2 = small + 256;
    float* attf0 = small + 384;    float* attf1 = small + 448;   float* attf2 = small + 512;
    float* bf0   = small + 576;    float* bf1   = small + 640;   float* bf2   = small + 704;
    float* WROf  = small + 768;    float* brof  = small + 1408;

    detect_kernel<<<dim3(1), dim3(64), 0, stream>>>((const unsigned*)Wl0, flag);

    preconvert<<<dim3(134), dim3(256), 0, stream>>>(
        Wl0, Wr0, Wl1, Wr1, Wl2, Wr2, bl0, br0, bl1, br1, bl2, br2,
        at0, at1, at2, b0, b1, b2, Wro, bro, WT0, WT1, WT2, small, flag);

    // deterministic edge sort: chunk hist -> chunk scan -> bucket scan ->
    // deterministic partition -> per-bucket fine hist/scan/scatter
    chunkhist_kernel<<<dim3(NCH), dim3(256), 0, stream>>>(dstArr, chunkcnt);
    cscan_kernel<<<dim3(NBUK), dim3(1024), 0, stream>>>(chunkcnt, bucket_cnt);
    bscan_kernel<<<dim3(1), dim3(128), 0, stream>>>(bucket_cnt, bucket_base);
    part_kernel<<<dim3(NCH), dim3(256), 0, stream>>>(srcArr, dstArr, chunkcnt, bucket_base, part);
    hist_part_kernel<<<dim3(NBUK), dim3(256), 0, stream>>>(part, bucket_base, fillc);
    scan1<<<dim3(313), dim3(256), 0, stream>>>(fillc, rowptr, bsums);
    scan2<<<dim3(1), dim3(512), 0, stream>>>(bsums, 313);
    scan3<<<dim3(313), dim3(256), 0, stream>>>(rowptr, bsums);
    scatter2_kernel<<<dim3(NBUK), dim3(256), 0, stream>>>(part, bucket_base, rowptr, col2);

    // layer 0
    lin_fast<128, true><<<dim3(NN / 64), dim3(256), 0, stream>>>(x, WT0, biasLR0, xlh, xr, flag);
    score_kernel<<<dim3(EE / 256), dim3(256), 0, stream>>>(xlh, xr, attf0, col2, sq);
    agg2_kernel<false><<<dim3(NN / 4), dim3(256), 0, stream>>>(xlh, xr, attf0, bf0, rowptr, sq, hA,
                                                               WROf, brof, d_out, flag);
    // layer 1
    lin_fast<64, false><<<dim3(NN / 64), dim3(256), 0, stream>>>(hA, WT1, biasLR1, xlh, xr, flag);
    score_kernel<<<dim3(EE / 256), dim3(256), 0, stream>>>(xlh, xr, attf1, col2, sq);
    agg2_kernel<false><<<dim3(NN / 4), dim3(256), 0, stream>>>(xlh, xr, attf1, bf1, rowptr, sq, hA,
                                                               WROf, brof, d_out, flag);
    // layer 2
    lin_fast<64, false><<<dim3(NN / 64), dim3(256), 0, stream>>>(hA, WT2, biasLR2, xlh, xr, flag);
    score_kernel<<<dim3(EE / 256), dim3(256), 0, stream>>>(xlh, xr, attf2, col2, sq);
    agg2_kernel<true><<<dim3(NN / 4), dim3(256), 0, stream>>>(xlh, xr, attf2, bf2, rowptr, sq, hA,
                                                              WROf, brof, d_out, flag);
}